// Round 2
// baseline (765.410 us; speedup 1.0000x reference)
//
#include <hip/hip_runtime.h>

// ---------------------------------------------------------------------------
// GatheringLoss: phase-only FFT reconstruction -> dense score -> top-1 -> SSE
// queries: (8, 4096, 512) f32, items: (1024, 512) f32, out: (8, 4096) f32
//
// Math: unit = irfft(exp(-1j*angle(rfft(q)))) == real(FFT(X/|X|))/N where
// X = FFT(q) full complex spectrum (verified via Hermitian symmetry).
// ---------------------------------------------------------------------------

#define NB 8
#define NS 4096
#define NF 512
#define NK 1024
#define NROWS (NB * NS)      // 32768
#define NKB 8                // k-chunks of 128

// LDS bank-derotation: bijective within each aligned 16-elem block.
// Verified per-stage: makes Stockham stage-0/1 writes (naive 16-way) and all
// reads ~conflict-free for float2 (b64) access.
#define SWZ(i) ((((i) & ~15)) | (((i) + 5 * ((i) >> 4)) & 15))

__device__ __forceinline__ float2 cmulf(float2 a, float2 b) {
    return make_float2(a.x * b.x - a.y * b.y, a.x * b.y + a.y * b.x);
}

// ---------------------------------------------------------------------------
// Kernel 1: twiddle table W[k] = exp(-2*pi*i*k/4096), computed in fp64
// ---------------------------------------------------------------------------
__global__ void twiddle_init(float2* __restrict__ W) {
    int k = blockIdx.x * 256 + threadIdx.x;   // 4096 total
    double ang = -2.0 * 3.14159265358979323846 * (double)k / 4096.0;
    W[k] = make_float2((float)cos(ang), (float)sin(ang));
}

// ---------------------------------------------------------------------------
// Kernel 2: transpose (b, s, f) -> (b, f, s), 32x32 tiles
// ---------------------------------------------------------------------------
__global__ __launch_bounds__(256) void transpose_kernel(
        const float* __restrict__ q, float* __restrict__ qt) {
    __shared__ float tile[32][33];
    int b = blockIdx.z;
    int s0 = blockIdx.x * 32;
    int f0 = blockIdx.y * 32;
    int tx = threadIdx.x;            // 0..31
    int ty = threadIdx.y;            // 0..7
    const float* qb = q + (size_t)b * NS * NF;
    float* qtb = qt + (size_t)b * NF * NS;
#pragma unroll
    for (int i = 0; i < 4; ++i) {
        int s = s0 + ty + i * 8;
        tile[ty + i * 8][tx] = qb[(size_t)s * NF + f0 + tx];
    }
    __syncthreads();
#pragma unroll
    for (int i = 0; i < 4; ++i) {
        int f = f0 + ty + i * 8;
        qtb[(size_t)f * NS + s0 + tx] = tile[tx][ty + i * 8];
    }
}

// ---------------------------------------------------------------------------
// Kernel 3: per-row 4096-pt FFT -> phase normalize -> FFT -> real/N, in place
// Radix-4 Stockham (DIF autosort), 6 stages, 256 threads, 4 butterflies/thr.
// Stage s=4^st: src {bi, bi+1024, bi+2048, bi+3072}; q=bi&(s-1);
// dst base = 4*bi-3*q; twiddle W[(j*(bi-q)) & 4095] on output j.
// Even stage count -> result lands back in A, natural order.
// ---------------------------------------------------------------------------
__device__ __forceinline__ void fft4096(float2* A, float2* B,
                                        const float2* __restrict__ W, int t) {
    float2* src = A;
    float2* dst = B;
#pragma unroll
    for (int st = 0; st < 6; ++st) {
        const int s = 1 << (2 * st);
        __syncthreads();
#pragma unroll
        for (int j = 0; j < 4; ++j) {
            int bi = t + j * 256;
            float2 a = src[SWZ(bi)];
            float2 b = src[SWZ(bi + 1024)];
            float2 c = src[SWZ(bi + 2048)];
            float2 d = src[SWZ(bi + 3072)];
            float2 apc = make_float2(a.x + c.x, a.y + c.y);
            float2 amc = make_float2(a.x - c.x, a.y - c.y);
            float2 bpd = make_float2(b.x + d.x, b.y + d.y);
            float2 bmd = make_float2(b.x - d.x, b.y - d.y);
            float2 x0 = make_float2(apc.x + bpd.x, apc.y + bpd.y);
            float2 x1 = make_float2(amc.x + bmd.y, amc.y - bmd.x);  // amc - i*bmd
            float2 x2 = make_float2(apc.x - bpd.x, apc.y - bpd.y);
            float2 x3 = make_float2(amc.x - bmd.y, amc.y + bmd.x);  // amc + i*bmd
            int q = bi & (s - 1);
            int pw = bi - q;                   // p*s
            int dbase = 4 * bi - 3 * q;
            float2 w1 = W[pw & 4095];
            float2 w2 = W[(2 * pw) & 4095];
            float2 w3 = W[(3 * pw) & 4095];
            dst[SWZ(dbase)] = x0;
            dst[SWZ(dbase + s)] = cmulf(w1, x1);
            dst[SWZ(dbase + 2 * s)] = cmulf(w2, x2);
            dst[SWZ(dbase + 3 * s)] = cmulf(w3, x3);
        }
        float2* tmp = src; src = dst; dst = tmp;
    }
}

__global__ __launch_bounds__(256) void fft_phase_kernel(
        float* __restrict__ qt, const float2* __restrict__ W) {
    __shared__ float2 bufA[4096];
    __shared__ float2 bufB[4096];
    const int t = threadIdx.x;
    float* x = qt + (size_t)blockIdx.x * NS;

    const float4* x4 = (const float4*)x;
#pragma unroll
    for (int i = 0; i < 4; ++i) {
        int idx = t + i * 256;
        float4 v = x4[idx];
        bufA[SWZ(idx * 4 + 0)] = make_float2(v.x, 0.f);
        bufA[SWZ(idx * 4 + 1)] = make_float2(v.y, 0.f);
        bufA[SWZ(idx * 4 + 2)] = make_float2(v.z, 0.f);
        bufA[SWZ(idx * 4 + 3)] = make_float2(v.w, 0.f);
    }

    fft4096(bufA, bufB, W, t);       // X in bufA (natural order)
    __syncthreads();

    // Z = X/|X| (zero -> 1, matching exp(-1j*angle(0)) = 1)
#pragma unroll
    for (int i = 0; i < 16; ++i) {
        int idx = SWZ(t + i * 256);
        float2 v = bufA[idx];
        float m2 = v.x * v.x + v.y * v.y;
        float2 z;
        if (m2 > 0.f) {
            float inv = 1.0f / sqrtf(m2);
            z = make_float2(v.x * inv, v.y * inv);
        } else {
            z = make_float2(1.f, 0.f);
        }
        bufA[idx] = z;
    }

    fft4096(bufA, bufB, W, t);       // FFT(Z) in bufA; unit = real/4096
    __syncthreads();

    float4* o4 = (float4*)x;
    const float scale = 1.0f / 4096.0f;
#pragma unroll
    for (int i = 0; i < 4; ++i) {
        int idx = t + i * 256;
        float4 v;
        v.x = bufA[SWZ(idx * 4 + 0)].x * scale;
        v.y = bufA[SWZ(idx * 4 + 1)].x * scale;
        v.z = bufA[SWZ(idx * 4 + 2)].x * scale;
        v.w = bufA[SWZ(idx * 4 + 3)].x * scale;
        o4[idx] = v;
    }
}

// ---------------------------------------------------------------------------
// Kernel 4: score GEMM (unit . itemsT) fused with per-(row, kchunk) argmax.
// Block: 64 s-rows x 128 k. Thread: 4s x 8k microtile. f staged in chunks of 32.
// Tie-break: ascending k, strict '>' -> first max (numpy semantics).
// ---------------------------------------------------------------------------
__global__ __launch_bounds__(256) void gemm_argmax_kernel(
        const float* __restrict__ unit_t, const float* __restrict__ items,
        float* __restrict__ pbest, int* __restrict__ pidx) {
    __shared__ float As[32][64];      // 8 KB    [f][s]
    __shared__ float Bs[32][132];     // 16.5 KB [f][k], pad->bank spread
    __shared__ float bv[16][64];      // 4 KB
    __shared__ int bix[16][64];       // 4 KB

    const int sb = blockIdx.x;        // 0..511
    const int kb = blockIdx.y;        // 0..7
    const int row0 = sb * 64;
    const int b = row0 >> 12;         // 4096 % 64 == 0 -> whole block same b
    const int s0 = row0 & (NS - 1);
    const int k0 = kb * 128;
    const int t = threadIdx.x;
    const int ts = t & 15;            // s group
    const int tk = t >> 4;            // k group

    float acc[4][8];
#pragma unroll
    for (int i = 0; i < 4; ++i)
#pragma unroll
        for (int k = 0; k < 8; ++k) acc[i][k] = 0.f;

    const float* Ab = unit_t + (size_t)b * NF * NS;

    for (int f0 = 0; f0 < NF; f0 += 32) {
        __syncthreads();
        // stage A: 32f x 64s, coalesced along s
#pragma unroll
        for (int i = 0; i < 8; ++i) {
            int idx = t + i * 256;
            int f = idx >> 6;
            int s = idx & 63;
            As[f][s] = Ab[(size_t)(f0 + f) * NS + s0 + s];
        }
        // stage B: items rows via float4, transpose to [f][k]
#pragma unroll
        for (int i = 0; i < 4; ++i) {
            int k = (t >> 3) + i * 32;
            int f = (t & 7) * 4;
            float4 v = *(const float4*)&items[(size_t)(k0 + k) * NF + f0 + f];
            Bs[f + 0][k] = v.x;
            Bs[f + 1][k] = v.y;
            Bs[f + 2][k] = v.z;
            Bs[f + 3][k] = v.w;
        }
        __syncthreads();
#pragma unroll
        for (int ff = 0; ff < 32; ++ff) {
            float4 a = *(const float4*)&As[ff][ts * 4];
            float4 b0 = *(const float4*)&Bs[ff][tk * 8];
            float4 b1 = *(const float4*)&Bs[ff][tk * 8 + 4];
            float av[4] = {a.x, a.y, a.z, a.w};
            float bvv[8] = {b0.x, b0.y, b0.z, b0.w, b1.x, b1.y, b1.z, b1.w};
#pragma unroll
            for (int i = 0; i < 4; ++i)
#pragma unroll
                for (int k = 0; k < 8; ++k) acc[i][k] += av[i] * bvv[k];
        }
    }

    __syncthreads();
    // per-thread argmax over its 8 ks (ascending, strict >)
#pragma unroll
    for (int i = 0; i < 4; ++i) {
        float best = acc[i][0];
        int bidx = 0;
#pragma unroll
        for (int k = 1; k < 8; ++k) {
            if (acc[i][k] > best) { best = acc[i][k]; bidx = k; }
        }
        bv[tk][ts * 4 + i] = best;
        bix[tk][ts * 4 + i] = tk * 8 + bidx;
    }
    __syncthreads();
    if (t < 64) {
        float best = bv[0][t];
        int bidx = bix[0][t];
#pragma unroll
        for (int g = 1; g < 16; ++g) {
            if (bv[g][t] > best) { best = bv[g][t]; bidx = bix[g][t]; }
        }
        int row = row0 + t;
        pbest[(size_t)row * NKB + kb] = best;
        pidx[(size_t)row * NKB + kb] = k0 + bidx;
    }
}

// ---------------------------------------------------------------------------
// Kernel 5: combine k-chunk partials (ascending, strict >) then
// loss[row] = sum_f (q[row][f] - items[idx][f])^2.  One wave per row.
// ---------------------------------------------------------------------------
__global__ __launch_bounds__(256) void combine_loss_kernel(
        const float* __restrict__ q, const float* __restrict__ items,
        const float* __restrict__ pbest, const int* __restrict__ pidx,
        float* __restrict__ out) {
    const int wid = threadIdx.x >> 6;
    const int lane = threadIdx.x & 63;
    const int row = blockIdx.x * 4 + wid;

    float best = pbest[(size_t)row * NKB];
    int bidx = pidx[(size_t)row * NKB];
#pragma unroll
    for (int g = 1; g < NKB; ++g) {
        float v = pbest[(size_t)row * NKB + g];
        if (v > best) { best = v; bidx = pidx[(size_t)row * NKB + g]; }
    }

    const float4* qr = (const float4*)(q + (size_t)row * NF);
    const float4* mr = (const float4*)(items + (size_t)bidx * NF);
    float sum = 0.f;
#pragma unroll
    for (int i = 0; i < 2; ++i) {
        float4 a = qr[lane + i * 64];
        float4 m = mr[lane + i * 64];
        float dx = a.x - m.x, dy = a.y - m.y, dz = a.z - m.z, dw = a.w - m.w;
        sum += dx * dx + dy * dy + dz * dz + dw * dw;
    }
#pragma unroll
    for (int off = 32; off; off >>= 1) sum += __shfl_down(sum, off, 64);
    if (lane == 0) out[row] = sum;
}

// ---------------------------------------------------------------------------
extern "C" void kernel_launch(void* const* d_in, const int* in_sizes, int n_in,
                              void* d_out, int out_size, void* d_ws, size_t ws_size,
                              hipStream_t stream) {
    const float* q = (const float*)d_in[0];      // (8,4096,512) f32
    const float* items = (const float*)d_in[1];  // (1024,512) f32
    float* out = (float*)d_out;                  // (8,4096) f32

    char* ws = (char*)d_ws;
    float2* W = (float2*)ws;                            // 32 KB
    float* qt = (float*)(ws + 32768);                   // 64 MB (b,f,s); unit in place
    float* pbest = (float*)(ws + 32768 + 67108864);     // 1 MB
    int* pidx = (int*)(ws + 32768 + 67108864 + 1048576);// 1 MB

    hipLaunchKernelGGL(twiddle_init, dim3(16), dim3(256), 0, stream, W);
    hipLaunchKernelGGL(transpose_kernel, dim3(128, 16, 8), dim3(32, 8, 1), 0,
                       stream, q, qt);
    hipLaunchKernelGGL(fft_phase_kernel, dim3(4096), dim3(256), 0, stream, qt, W);
    hipLaunchKernelGGL(gemm_argmax_kernel, dim3(512, 8), dim3(256), 0, stream,
                       qt, items, pbest, pidx);
    hipLaunchKernelGGL(combine_loss_kernel, dim3(NROWS / 4), dim3(256), 0,
                       stream, q, items, pbest, pidx, out);
}

// Round 4
// 633.906 us; speedup vs baseline: 1.2075x; 1.2075x over previous
//
#include <hip/hip_runtime.h>

// ---------------------------------------------------------------------------
// GatheringLoss: phase-only FFT reconstruction -> dense score -> top-1 -> SSE
// queries: (8, 4096, 512) f32, items: (1024, 512) f32, out: (8, 4096) f32
// unit = irfft(exp(-1j*angle(rfft(q)))) == real(FFT(X/|X|))/N, X = FFT(q).
// Two-for-one real FFTs: pass1 packs 2 real rows into one complex FFT;
// pass2 packs 2 Hermitian spectra (real outputs in Re/Im).
// ---------------------------------------------------------------------------

#define NB 8
#define NS 4096
#define NF 512
#define NK 1024
#define NROWS (NB * NS)      // 32768
#define NKB 8                // k-chunks of 128

// LDS bank-derotation for the FFT buffers (verified conflict-reducing for the
// Stockham stride patterns).
#define SWZ(i) ((((i) & ~15)) | (((i) + 5 * ((i) >> 4)) & 15))

__device__ __forceinline__ float2 cmulf(float2 a, float2 b) {
    return make_float2(a.x * b.x - a.y * b.y, a.x * b.y + a.y * b.x);
}

// X/|X|, with X==0 -> 1 (matches exp(-1j*angle(0)) == 1)
__device__ __forceinline__ float2 unitize(float2 v) {
    float m2 = v.x * v.x + v.y * v.y;
    if (m2 > 0.f) {
        float inv = 1.0f / sqrtf(m2);
        return make_float2(v.x * inv, v.y * inv);
    }
    return make_float2(1.f, 0.f);
}

// ---------------------------------------------------------------------------
// Kernel 1: twiddle table W[k] = exp(-2*pi*i*k/4096), fp64-computed
// ---------------------------------------------------------------------------
__global__ void twiddle_init(float2* __restrict__ W) {
    int k = blockIdx.x * 256 + threadIdx.x;
    double ang = -2.0 * 3.14159265358979323846 * (double)k / 4096.0;
    W[k] = make_float2((float)cos(ang), (float)sin(ang));
}

// ---------------------------------------------------------------------------
// Kernel 2: transpose (b, s, f) -> (b, f, s)
// ---------------------------------------------------------------------------
__global__ __launch_bounds__(256) void transpose_kernel(
        const float* __restrict__ q, float* __restrict__ qt) {
    __shared__ float tile[32][33];
    int b = blockIdx.z;
    int s0 = blockIdx.x * 32;
    int f0 = blockIdx.y * 32;
    int tx = threadIdx.x;
    int ty = threadIdx.y;
    const float* qb = q + (size_t)b * NS * NF;
    float* qtb = qt + (size_t)b * NF * NS;
#pragma unroll
    for (int i = 0; i < 4; ++i) {
        int s = s0 + ty + i * 8;
        tile[ty + i * 8][tx] = qb[(size_t)s * NF + f0 + tx];
    }
    __syncthreads();
#pragma unroll
    for (int i = 0; i < 4; ++i) {
        int f = f0 + ty + i * 8;
        qtb[(size_t)f * NS + s0 + tx] = tile[tx][ty + i * 8];
    }
}

// ---------------------------------------------------------------------------
// Radix-4 Stockham 4096-pt FFT, 6 stages, 256 threads. Result back in A.
// ---------------------------------------------------------------------------
__device__ __forceinline__ void fft4096(float2* A, float2* B,
                                        const float2* __restrict__ W, int t) {
    float2* src = A;
    float2* dst = B;
#pragma unroll
    for (int st = 0; st < 6; ++st) {
        const int s = 1 << (2 * st);
        __syncthreads();
#pragma unroll
        for (int j = 0; j < 4; ++j) {
            int bi = t + j * 256;
            float2 a = src[SWZ(bi)];
            float2 b = src[SWZ(bi + 1024)];
            float2 c = src[SWZ(bi + 2048)];
            float2 d = src[SWZ(bi + 3072)];
            float2 apc = make_float2(a.x + c.x, a.y + c.y);
            float2 amc = make_float2(a.x - c.x, a.y - c.y);
            float2 bpd = make_float2(b.x + d.x, b.y + d.y);
            float2 bmd = make_float2(b.x - d.x, b.y - d.y);
            float2 x0 = make_float2(apc.x + bpd.x, apc.y + bpd.y);
            float2 x1 = make_float2(amc.x + bmd.y, amc.y - bmd.x);
            float2 x2 = make_float2(apc.x - bpd.x, apc.y - bpd.y);
            float2 x3 = make_float2(amc.x - bmd.y, amc.y + bmd.x);
            int q = bi & (s - 1);
            int pw = bi - q;
            int dbase = 4 * bi - 3 * q;
            float2 w1 = W[pw & 4095];
            float2 w2 = W[(2 * pw) & 4095];
            float2 w3 = W[(3 * pw) & 4095];
            dst[SWZ(dbase)] = x0;
            dst[SWZ(dbase + s)] = cmulf(w1, x1);
            dst[SWZ(dbase + 2 * s)] = cmulf(w2, x2);
            dst[SWZ(dbase + 3 * s)] = cmulf(w3, x3);
        }
        float2* tmp = src; src = dst; dst = tmp;
    }
}

// ---------------------------------------------------------------------------
// Kernel 3: two rows per block (two-for-one real FFT both directions)
// ---------------------------------------------------------------------------
__global__ __launch_bounds__(256) void fft_phase_kernel(
        float* __restrict__ qt, const float2* __restrict__ W) {
    __shared__ float2 bufA[4096];
    __shared__ float2 bufB[4096];
    const int t = threadIdx.x;
    float* x0 = qt + (size_t)(2 * blockIdx.x) * NS;
    float* x1 = x0 + NS;

    const float4* a4 = (const float4*)x0;
    const float4* b4 = (const float4*)x1;
#pragma unroll
    for (int i = 0; i < 4; ++i) {
        int idx = t + i * 256;
        float4 va = a4[idx];
        float4 vb = b4[idx];
        bufA[SWZ(idx * 4 + 0)] = make_float2(va.x, vb.x);
        bufA[SWZ(idx * 4 + 1)] = make_float2(va.y, vb.y);
        bufA[SWZ(idx * 4 + 2)] = make_float2(va.z, vb.z);
        bufA[SWZ(idx * 4 + 3)] = make_float2(va.w, vb.w);
    }

    fft4096(bufA, bufB, W, t);          // Z = FFT(x0 + i*x1)
    __syncthreads();

    // Unpack X0, X1; normalize; repack V = U0 + i*U1 (both Hermitian).
#pragma unroll
    for (int j = 0; j < 8; ++j) {
        int k = t + j * 256;            // 0..2047
        if (k == 0) {
            float2 z0 = bufA[SWZ(0)];
            float2 zh = bufA[SWZ(2048)];
            float2 u00 = unitize(make_float2(z0.x, 0.f));
            float2 u10 = unitize(make_float2(z0.y, 0.f));
            bufA[SWZ(0)] = make_float2(u00.x, u10.x);
            float2 u0h = unitize(make_float2(zh.x, 0.f));
            float2 u1h = unitize(make_float2(zh.y, 0.f));
            bufA[SWZ(2048)] = make_float2(u0h.x, u1h.x);
        } else {
            float2 zk = bufA[SWZ(k)];
            float2 zm = bufA[SWZ(4096 - k)];
            // X0[k] = (Zk + conj(Zm))/2 ; X1[k] = -i*(Zk - conj(Zm))/2
            float2 a = make_float2(0.5f * (zk.x + zm.x), 0.5f * (zk.y - zm.y));
            float2 bq = make_float2(0.5f * (zk.x - zm.x), 0.5f * (zk.y + zm.y));
            float2 x1k = make_float2(bq.y, -bq.x);
            float2 u0 = unitize(a);
            float2 u1 = unitize(x1k);
            // V[k] = U0 + i*U1 ; V[N-k] = conj(U0) + i*conj(U1)
            bufA[SWZ(k)] = make_float2(u0.x - u1.y, u0.y + u1.x);
            bufA[SWZ(4096 - k)] = make_float2(u0.x + u1.y, u1.x - u0.y);
        }
    }

    fft4096(bufA, bufB, W, t);          // F = FFT(V) = u0*N + i*u1*N
    __syncthreads();

    float4* o0 = (float4*)x0;
    float4* o1 = (float4*)x1;
    const float scale = 1.0f / 4096.0f;
#pragma unroll
    for (int i = 0; i < 4; ++i) {
        int idx = t + i * 256;
        float2 e0 = bufA[SWZ(idx * 4 + 0)];
        float2 e1 = bufA[SWZ(idx * 4 + 1)];
        float2 e2 = bufA[SWZ(idx * 4 + 2)];
        float2 e3 = bufA[SWZ(idx * 4 + 3)];
        o0[idx] = make_float4(e0.x * scale, e1.x * scale, e2.x * scale, e3.x * scale);
        o1[idx] = make_float4(e0.y * scale, e1.y * scale, e2.y * scale, e3.y * scale);
    }
}

// ---------------------------------------------------------------------------
// Kernel 4: score GEMM + per-(row, kchunk) argmax.
// 128s x 128k block tile, 256 threads, 8x8 microtile.
// Thread (ts=t&15, tk=t>>4): s = 4*ts + c + 64*j (c 0..3, j 0..1),
//                            k = 8*tk + kk.
// ---------------------------------------------------------------------------
__global__ __launch_bounds__(256, 4) void gemm_argmax_kernel(
        const float* __restrict__ unit_t, const float* __restrict__ items,
        float* __restrict__ pbest, int* __restrict__ pidx) {
    __shared__ __align__(16) float smem[4096 + 32 * 132];   // 33.3 KB
    float (*As)[128] = (float (*)[128])smem;                // [f][s]
    float (*Bs)[132] = (float (*)[132])(smem + 4096);       // [f][k]

    const int kb = blockIdx.x;        // 0..7  (fastest -> k-blocks share A panel)
    const int sb = blockIdx.y;        // 0..255
    const int row0 = sb * 128;
    const int b = row0 >> 12;         // 128 | 4096 -> whole block same b
    const int s0 = row0 & (NS - 1);
    const int k0 = kb * 128;
    const int t = threadIdx.x;
    const int ts = t & 15;
    const int tk = t >> 4;

    float acc[8][8];
#pragma unroll
    for (int i = 0; i < 8; ++i)
#pragma unroll
        for (int k = 0; k < 8; ++k) acc[i][k] = 0.f;

    const float* Ab = unit_t + (size_t)b * NF * NS + s0;

    const int sA = (t & 31) * 4;      // A-stage: float4 along s
    const int fA = t >> 5;
    const int kB = t >> 3;            // B-stage: float4 along f, transpose
    const int fB = (t & 7) * 4;

    for (int f0 = 0; f0 < NF; f0 += 32) {
        __syncthreads();
#pragma unroll
        for (int i = 0; i < 4; ++i) {
            int f = fA + i * 8;
            float4 v = *(const float4*)&Ab[(size_t)(f0 + f) * NS + sA];
            *(float4*)&As[f][sA] = v;
        }
#pragma unroll
        for (int i = 0; i < 4; ++i) {
            int k = kB + i * 32;
            float4 v = *(const float4*)&items[(size_t)(k0 + k) * NF + f0 + fB];
            Bs[fB + 0][k] = v.x;
            Bs[fB + 1][k] = v.y;
            Bs[fB + 2][k] = v.z;
            Bs[fB + 3][k] = v.w;
        }
        __syncthreads();
#pragma unroll
        for (int ff = 0; ff < 32; ++ff) {
            float4 a0 = *(const float4*)&As[ff][ts * 4];
            float4 a1 = *(const float4*)&As[ff][ts * 4 + 64];
            float4 b0 = *(const float4*)&Bs[ff][tk * 8];
            float4 b1 = *(const float4*)&Bs[ff][tk * 8 + 4];
            float av[8] = {a0.x, a0.y, a0.z, a0.w, a1.x, a1.y, a1.z, a1.w};
            float bw[8] = {b0.x, b0.y, b0.z, b0.w, b1.x, b1.y, b1.z, b1.w};
#pragma unroll
            for (int i = 0; i < 8; ++i)
#pragma unroll
                for (int k = 0; k < 8; ++k) acc[i][k] += av[i] * bw[k];
        }
    }

    __syncthreads();                  // done with As/Bs; reuse smem
    float (*bv)[128] = (float (*)[128])smem;
    int (*bix)[128] = (int (*)[128])(smem + 2048);

#pragma unroll
    for (int r = 0; r < 8; ++r) {
        int s_local = ts * 4 + (r & 3) + 64 * (r >> 2);
        float best = acc[r][0];
        int bidx = 0;
#pragma unroll
        for (int k = 1; k < 8; ++k) {
            if (acc[r][k] > best) { best = acc[r][k]; bidx = k; }
        }
        bv[tk][s_local] = best;
        bix[tk][s_local] = tk * 8 + bidx;
    }
    __syncthreads();
    if (t < 128) {
        float best = bv[0][t];
        int bidx = bix[0][t];
#pragma unroll
        for (int g = 1; g < 16; ++g) {
            if (bv[g][t] > best) { best = bv[g][t]; bidx = bix[g][t]; }
        }
        int row = row0 + t;
        pbest[(size_t)row * NKB + kb] = best;
        pidx[(size_t)row * NKB + kb] = k0 + bidx;
    }
}

// ---------------------------------------------------------------------------
// Kernel 5: combine partials (ascending k, strict >) + SSE vs queries
// ---------------------------------------------------------------------------
__global__ __launch_bounds__(256) void combine_loss_kernel(
        const float* __restrict__ q, const float* __restrict__ items,
        const float* __restrict__ pbest, const int* __restrict__ pidx,
        float* __restrict__ out) {
    const int wid = threadIdx.x >> 6;
    const int lane = threadIdx.x & 63;
    const int row = blockIdx.x * 4 + wid;

    float best = pbest[(size_t)row * NKB];
    int bidx = pidx[(size_t)row * NKB];
#pragma unroll
    for (int g = 1; g < NKB; ++g) {
        float v = pbest[(size_t)row * NKB + g];
        if (v > best) { best = v; bidx = pidx[(size_t)row * NKB + g]; }
    }

    const float4* qr = (const float4*)(q + (size_t)row * NF);
    const float4* mr = (const float4*)(items + (size_t)bidx * NF);
    float sum = 0.f;
#pragma unroll
    for (int i = 0; i < 2; ++i) {
        float4 a = qr[lane + i * 64];
        float4 m = mr[lane + i * 64];
        float dx = a.x - m.x, dy = a.y - m.y, dz = a.z - m.z, dw = a.w - m.w;
        sum += dx * dx + dy * dy + dz * dz + dw * dw;
    }
#pragma unroll
    for (int off = 32; off; off >>= 1) sum += __shfl_down(sum, off, 64);
    if (lane == 0) out[row] = sum;
}

// ---------------------------------------------------------------------------
extern "C" void kernel_launch(void* const* d_in, const int* in_sizes, int n_in,
                              void* d_out, int out_size, void* d_ws, size_t ws_size,
                              hipStream_t stream) {
    const float* q = (const float*)d_in[0];
    const float* items = (const float*)d_in[1];
    float* out = (float*)d_out;

    char* ws = (char*)d_ws;
    float2* W = (float2*)ws;                             // 32 KB
    float* qt = (float*)(ws + 32768);                    // 64 MB (b,f,s); unit in place
    float* pbest = (float*)(ws + 32768 + 67108864);      // 1 MB
    int* pidx = (int*)(ws + 32768 + 67108864 + 1048576); // 1 MB

    hipLaunchKernelGGL(twiddle_init, dim3(16), dim3(256), 0, stream, W);
    hipLaunchKernelGGL(transpose_kernel, dim3(128, 16, 8), dim3(32, 8, 1), 0,
                       stream, q, qt);
    hipLaunchKernelGGL(fft_phase_kernel, dim3(2048), dim3(256), 0, stream, qt, W);
    hipLaunchKernelGGL(gemm_argmax_kernel, dim3(8, 256), dim3(256), 0, stream,
                       qt, items, pbest, pidx);
    hipLaunchKernelGGL(combine_loss_kernel, dim3(NROWS / 4), dim3(256), 0,
                       stream, q, items, pbest, pidx, out);
}

// Round 5
// 466.655 us; speedup vs baseline: 1.6402x; 1.3584x over previous
//
#include <hip/hip_runtime.h>

// ---------------------------------------------------------------------------
// GatheringLoss: phase-only FFT reconstruction -> dense score -> top-1 -> SSE
// queries: (8, 4096, 512) f32, items: (1024, 512) f32, out: (8, 4096) f32
// unit = irfft(exp(-1j*angle(rfft(q)))) == real(FFT(X/|X|))/N, X = FFT(q).
// Score GEMM runs on MFMA f16 with exact 2-way split (3 products, lo*lo
// omitted; both operands pre-scaled by 2^10 -> argmax invariant).
// ---------------------------------------------------------------------------

#define NB 8
#define NS 4096
#define NF 512
#define NK 1024
#define NROWS (NB * NS)      // 32768
#define NKB 8                // n-chunks of 128
#define KK 1024              // A'' row length in halves ([Ahi(512) | Alo(512)])

// LDS bank-derotation for the FFT buffers.
#define SWZ(i) ((((i) & ~15)) | (((i) + 5 * ((i) >> 4)) & 15))

typedef _Float16 half8 __attribute__((ext_vector_type(8)));
typedef float floatx4 __attribute__((ext_vector_type(4)));
struct H2 { _Float16 x, y; };   // (hi, lo)

__device__ __forceinline__ float2 cmulf(float2 a, float2 b) {
    return make_float2(a.x * b.x - a.y * b.y, a.x * b.y + a.y * b.x);
}

__device__ __forceinline__ float2 unitize(float2 v) {
    float m2 = v.x * v.x + v.y * v.y;
    if (m2 > 0.f) {
        float inv = 1.0f / sqrtf(m2);
        return make_float2(v.x * inv, v.y * inv);
    }
    return make_float2(1.f, 0.f);
}

__device__ __forceinline__ H2 split_h2(float v) {
    _Float16 h = (_Float16)v;
    float lo = v - (float)h;
    H2 r; r.x = h; r.y = (_Float16)lo; return r;
}

// ---------------------------------------------------------------------------
// Kernel 1: twiddle table
// ---------------------------------------------------------------------------
__global__ void twiddle_init(float2* __restrict__ W) {
    int k = blockIdx.x * 256 + threadIdx.x;
    double ang = -2.0 * 3.14159265358979323846 * (double)k / 4096.0;
    W[k] = make_float2((float)cos(ang), (float)sin(ang));
}

// ---------------------------------------------------------------------------
// Kernel 2: transpose (b, s, f) -> (b, f, s) fp32
// ---------------------------------------------------------------------------
__global__ __launch_bounds__(256) void transpose_kernel(
        const float* __restrict__ q, float* __restrict__ qt) {
    __shared__ float tile[32][33];
    int b = blockIdx.z;
    int s0 = blockIdx.x * 32;
    int f0 = blockIdx.y * 32;
    int tx = threadIdx.x;
    int ty = threadIdx.y;
    const float* qb = q + (size_t)b * NS * NF;
    float* qtb = qt + (size_t)b * NF * NS;
#pragma unroll
    for (int i = 0; i < 4; ++i) {
        int s = s0 + ty + i * 8;
        tile[ty + i * 8][tx] = qb[(size_t)s * NF + f0 + tx];
    }
    __syncthreads();
#pragma unroll
    for (int i = 0; i < 4; ++i) {
        int f = f0 + ty + i * 8;
        qtb[(size_t)f * NS + s0 + tx] = tile[tx][ty + i * 8];
    }
}

// ---------------------------------------------------------------------------
// Radix-4 Stockham 4096-pt FFT, 6 stages, 256 threads. Result back in A.
// ---------------------------------------------------------------------------
__device__ __forceinline__ void fft4096(float2* A, float2* B,
                                        const float2* __restrict__ W, int t) {
    float2* src = A;
    float2* dst = B;
#pragma unroll
    for (int st = 0; st < 6; ++st) {
        const int s = 1 << (2 * st);
        __syncthreads();
#pragma unroll
        for (int j = 0; j < 4; ++j) {
            int bi = t + j * 256;
            float2 a = src[SWZ(bi)];
            float2 b = src[SWZ(bi + 1024)];
            float2 c = src[SWZ(bi + 2048)];
            float2 d = src[SWZ(bi + 3072)];
            float2 apc = make_float2(a.x + c.x, a.y + c.y);
            float2 amc = make_float2(a.x - c.x, a.y - c.y);
            float2 bpd = make_float2(b.x + d.x, b.y + d.y);
            float2 bmd = make_float2(b.x - d.x, b.y - d.y);
            float2 x0 = make_float2(apc.x + bpd.x, apc.y + bpd.y);
            float2 x1 = make_float2(amc.x + bmd.y, amc.y - bmd.x);
            float2 x2 = make_float2(apc.x - bpd.x, apc.y - bpd.y);
            float2 x3 = make_float2(amc.x - bmd.y, amc.y + bmd.x);
            int q = bi & (s - 1);
            int pw = bi - q;
            int dbase = 4 * bi - 3 * q;
            float2 w1 = W[pw & 4095];
            float2 w2 = W[(2 * pw) & 4095];
            float2 w3 = W[(3 * pw) & 4095];
            dst[SWZ(dbase)] = x0;
            dst[SWZ(dbase + s)] = cmulf(w1, x1);
            dst[SWZ(dbase + 2 * s)] = cmulf(w2, x2);
            dst[SWZ(dbase + 3 * s)] = cmulf(w3, x3);
        }
        float2* tmp = src; src = dst; dst = tmp;
    }
}

// ---------------------------------------------------------------------------
// Kernel 3: two rows per block; epilogue emits scaled fp16 (hi,lo) splits.
// U2 layout: [flat_row = b*512+f][s] of H2.  a' = 1024*unit = Re(F)*0.25.
// ---------------------------------------------------------------------------
__global__ __launch_bounds__(256) void fft_phase_kernel(
        const float* __restrict__ qt, H2* __restrict__ u2,
        const float2* __restrict__ W) {
    __shared__ float2 bufA[4096];
    __shared__ float2 bufB[4096];
    const int t = threadIdx.x;
    const float* x0 = qt + (size_t)(2 * blockIdx.x) * NS;
    const float* x1 = x0 + NS;

    const float4* a4 = (const float4*)x0;
    const float4* b4 = (const float4*)x1;
#pragma unroll
    for (int i = 0; i < 4; ++i) {
        int idx = t + i * 256;
        float4 va = a4[idx];
        float4 vb = b4[idx];
        bufA[SWZ(idx * 4 + 0)] = make_float2(va.x, vb.x);
        bufA[SWZ(idx * 4 + 1)] = make_float2(va.y, vb.y);
        bufA[SWZ(idx * 4 + 2)] = make_float2(va.z, vb.z);
        bufA[SWZ(idx * 4 + 3)] = make_float2(va.w, vb.w);
    }

    fft4096(bufA, bufB, W, t);          // Z = FFT(x0 + i*x1)
    __syncthreads();

#pragma unroll
    for (int j = 0; j < 8; ++j) {
        int k = t + j * 256;            // 0..2047
        if (k == 0) {
            float2 z0 = bufA[SWZ(0)];
            float2 zh = bufA[SWZ(2048)];
            float2 u00 = unitize(make_float2(z0.x, 0.f));
            float2 u10 = unitize(make_float2(z0.y, 0.f));
            bufA[SWZ(0)] = make_float2(u00.x, u10.x);
            float2 u0h = unitize(make_float2(zh.x, 0.f));
            float2 u1h = unitize(make_float2(zh.y, 0.f));
            bufA[SWZ(2048)] = make_float2(u0h.x, u1h.x);
        } else {
            float2 zk = bufA[SWZ(k)];
            float2 zm = bufA[SWZ(4096 - k)];
            float2 a = make_float2(0.5f * (zk.x + zm.x), 0.5f * (zk.y - zm.y));
            float2 bq = make_float2(0.5f * (zk.x - zm.x), 0.5f * (zk.y + zm.y));
            float2 x1k = make_float2(bq.y, -bq.x);
            float2 u0 = unitize(a);
            float2 u1 = unitize(x1k);
            bufA[SWZ(k)] = make_float2(u0.x - u1.y, u0.y + u1.x);
            bufA[SWZ(4096 - k)] = make_float2(u0.x + u1.y, u1.x - u0.y);
        }
    }

    fft4096(bufA, bufB, W, t);          // F = FFT(V) = u0*N + i*u1*N
    __syncthreads();

    H2* o0 = u2 + (size_t)(2 * blockIdx.x) * NS;
    H2* o1 = o0 + NS;
    const float c = 0.25f;              // (1/4096) * 1024
#pragma unroll
    for (int i = 0; i < 4; ++i) {
        int idx = t + i * 256;
        H2 t0[4], t1[4];
#pragma unroll
        for (int k = 0; k < 4; ++k) {
            float2 e = bufA[SWZ(idx * 4 + k)];
            t0[k] = split_h2(e.x * c);
            t1[k] = split_h2(e.y * c);
        }
        *(float4*)&o0[idx * 4] = *(float4*)t0;
        *(float4*)&o1[idx * 4] = *(float4*)t1;
    }
}

// ---------------------------------------------------------------------------
// Kernel 4: A''-builder: U2 [f][s] (H2) -> A'' [row=b*4096+s][ Ahi | Alo ]
// 64f x 64s tiles via LDS.
// ---------------------------------------------------------------------------
__global__ __launch_bounds__(256) void abuild_kernel(
        const H2* __restrict__ u2, _Float16* __restrict__ a2) {
    __shared__ H2 tile[64][65];
    const int b = blockIdx.z;
    const int f0 = blockIdx.y * 64;
    const int s0 = blockIdx.x * 64;
    const int t = threadIdx.x;
    const int fr = t >> 6;        // 0..3
    const int sc = t & 63;
#pragma unroll
    for (int i = 0; i < 16; ++i) {
        int f = fr + i * 4;
        tile[f][sc] = u2[(size_t)(b * NF + f0 + f) * NS + s0 + sc];
    }
    __syncthreads();
    const int s = t >> 2;         // 0..63
    const int qd = t & 3;         // 0..3 -> f block of 16
    _Float16 xs[16], ys[16];
#pragma unroll
    for (int j = 0; j < 16; ++j) {
        H2 v = tile[qd * 16 + j][s];
        xs[j] = v.x;
        ys[j] = v.y;
    }
    size_t rowoff = ((size_t)(b * NS + s0 + s)) * KK;
    _Float16* pr = a2 + rowoff + (f0 + qd * 16);
    *(float4*)&pr[0] = ((float4*)xs)[0];
    *(float4*)&pr[8] = ((float4*)xs)[1];
    _Float16* pl = pr + 512;
    *(float4*)&pl[0] = ((float4*)ys)[0];
    *(float4*)&pl[8] = ((float4*)ys)[1];
}

// ---------------------------------------------------------------------------
// Kernel 5: B''-builder: items [n][f] f32 -> B'' [n][ Bhi(512) | Blo(512) ]
// ---------------------------------------------------------------------------
__global__ __launch_bounds__(256) void bbuild_kernel(
        const float* __restrict__ items, _Float16* __restrict__ b2) {
    int id = blockIdx.x * 256 + threadIdx.x;   // 1024*128
    int n = id >> 7, fq = id & 127;
    float4 v = *(const float4*)&items[(size_t)n * NF + fq * 4];
    H2 h0 = split_h2(v.x * 1024.f);
    H2 h1 = split_h2(v.y * 1024.f);
    H2 h2v = split_h2(v.z * 1024.f);
    H2 h3 = split_h2(v.w * 1024.f);
    _Float16 hs[4] = {h0.x, h1.x, h2v.x, h3.x};
    _Float16 ls[4] = {h0.y, h1.y, h2v.y, h3.y};
    _Float16* pr = b2 + (size_t)n * KK + fq * 4;
    *(float2*)pr = *(float2*)hs;
    *(float2*)(pr + 512) = *(float2*)ls;
}

// ---------------------------------------------------------------------------
// Kernel 6: MFMA score GEMM + fused per-(row, n-chunk) argmax.
// Block 128 rows x 128 n, 4 waves (2x2), per-wave 64x64 = 4x4 MFMA frags.
// Logical K = 1536 over 3 segments: (Ahi,Bhi), (Alo,Bhi), (Ahi,Blo).
// LDS rows padded to 144 B -> frag ds_read_b128 is 2-way (free).
// ---------------------------------------------------------------------------
__global__ __launch_bounds__(256, 3) void gemm_mfma_argmax(
        const _Float16* __restrict__ a2, const _Float16* __restrict__ b2,
        float* __restrict__ pbest, int* __restrict__ pidx) {
    __shared__ __align__(16) char smem[2 * 128 * 144];   // 36 KB
    char* As = smem;
    char* Bs = smem + 128 * 144;

    const int kb = blockIdx.x;      // 0..7
    const int sb = blockIdx.y;      // 0..255
    const int row0 = sb * 128;
    const int n0 = kb * 128;
    const int t = threadIdx.x;
    const int wid = t >> 6, l = t & 63, g = l >> 4, c = l & 15;
    const int wr = wid >> 1, wc = wid & 1;

    floatx4 acc[4][4];
#pragma unroll
    for (int m = 0; m < 4; ++m)
#pragma unroll
        for (int n = 0; n < 4; ++n) acc[m][n] = (floatx4)0.f;

    const int sr = t >> 1;          // staging row 0..127
    const int sp = t & 1;           // staging part (64 B each)

    for (int ch = 0; ch < 24; ++ch) {
        const int seg = ch >> 3;
        const int kin = (ch & 7) * 64;
        const int acol = kin + (seg == 1 ? 512 : 0);
        const int bcol = kin + (seg == 2 ? 512 : 0);
        __syncthreads();
        {
            const char* ga = (const char*)(a2 + (size_t)(row0 + sr) * KK + acol) + sp * 64;
            char* la = As + sr * 144 + sp * 64;
#pragma unroll
            for (int i = 0; i < 4; ++i)
                *(float4*)(la + i * 16) = *(const float4*)(ga + i * 16);
            const char* gb = (const char*)(b2 + (size_t)(n0 + sr) * KK + bcol) + sp * 64;
            char* lb = Bs + sr * 144 + sp * 64;
#pragma unroll
            for (int i = 0; i < 4; ++i)
                *(float4*)(lb + i * 16) = *(const float4*)(gb + i * 16);
        }
        __syncthreads();
#pragma unroll
        for (int kk = 0; kk < 2; ++kk) {
            half8 af[4], bf[4];
#pragma unroll
            for (int m = 0; m < 4; ++m)
                af[m] = *(const half8*)(As + (wr * 64 + m * 16 + c) * 144 + kk * 64 + g * 16);
#pragma unroll
            for (int n = 0; n < 4; ++n)
                bf[n] = *(const half8*)(Bs + (wc * 64 + n * 16 + c) * 144 + kk * 64 + g * 16);
#pragma unroll
            for (int m = 0; m < 4; ++m)
#pragma unroll
                for (int n = 0; n < 4; ++n)
                    acc[m][n] = __builtin_amdgcn_mfma_f32_16x16x32_f16(
                        af[m], bf[n], acc[m][n], 0, 0, 0);
        }
    }

    __syncthreads();
    float* cand = (float*)smem;            // [2][128]
    int* candi = (int*)(smem + 1024);      // [2][128]

#pragma unroll
    for (int m = 0; m < 4; ++m) {
#pragma unroll
        for (int r = 0; r < 4; ++r) {
            float best = acc[m][0][r];
            int bi = c;                    // n-frag 0, col c
#pragma unroll
            for (int n = 1; n < 4; ++n) {
                float v = acc[m][n][r];
                int ig = n * 16 + c;
                if (v > best) { best = v; bi = ig; }
            }
#pragma unroll
            for (int off = 1; off < 16; off <<= 1) {
                float ov = __shfl_xor(best, off);
                int oi = __shfl_xor(bi, off);
                if (ov > best || (ov == best && oi < bi)) { best = ov; bi = oi; }
            }
            if (c == 0) {
                int s_local = wr * 64 + m * 16 + 4 * g + r;
                cand[wc * 128 + s_local] = best;
                candi[wc * 128 + s_local] = bi;   // 0..63 within wave n-slice
            }
        }
    }
    __syncthreads();
    if (t < 128) {
        float b0v = cand[t];
        int b0i = candi[t];
        float b1v = cand[128 + t];
        int b1i = candi[128 + t] + 64;
        float best = b0v; int bi = b0i;
        if (b1v > b0v) { best = b1v; bi = b1i; }   // tie keeps lower (wc=0)
        int row = row0 + t;
        pbest[(size_t)row * NKB + kb] = best;
        pidx[(size_t)row * NKB + kb] = n0 + bi;
    }
}

// ---------------------------------------------------------------------------
// Kernel 7: combine partials (ascending n-chunk, strict >) + SSE vs queries
// ---------------------------------------------------------------------------
__global__ __launch_bounds__(256) void combine_loss_kernel(
        const float* __restrict__ q, const float* __restrict__ items,
        const float* __restrict__ pbest, const int* __restrict__ pidx,
        float* __restrict__ out) {
    const int wid = threadIdx.x >> 6;
    const int lane = threadIdx.x & 63;
    const int row = blockIdx.x * 4 + wid;

    float best = pbest[(size_t)row * NKB];
    int bidx = pidx[(size_t)row * NKB];
#pragma unroll
    for (int g = 1; g < NKB; ++g) {
        float v = pbest[(size_t)row * NKB + g];
        if (v > best) { best = v; bidx = pidx[(size_t)row * NKB + g]; }
    }

    const float4* qr = (const float4*)(q + (size_t)row * NF);
    const float4* mr = (const float4*)(items + (size_t)bidx * NF);
    float sum = 0.f;
#pragma unroll
    for (int i = 0; i < 2; ++i) {
        float4 a = qr[lane + i * 64];
        float4 m = mr[lane + i * 64];
        float dx = a.x - m.x, dy = a.y - m.y, dz = a.z - m.z, dw = a.w - m.w;
        sum += dx * dx + dy * dy + dz * dz + dw * dw;
    }
#pragma unroll
    for (int off = 32; off; off >>= 1) sum += __shfl_down(sum, off, 64);
    if (lane == 0) out[row] = sum;
}

// ---------------------------------------------------------------------------
extern "C" void kernel_launch(void* const* d_in, const int* in_sizes, int n_in,
                              void* d_out, int out_size, void* d_ws, size_t ws_size,
                              hipStream_t stream) {
    const float* q = (const float*)d_in[0];
    const float* items = (const float*)d_in[1];
    float* out = (float*)d_out;

    char* ws = (char*)d_ws;
    // Layout (132.1 MB total):
    //   [0]        W       32 KB
    //   [32K]      qt/A''  64 MB   (fp32 qt for FFT, then overwritten by A'')
    //   [32K+64M]  U2      64 MB   (H2 [4096][4096])
    //   [+64M]     B''      2 MB
    //   [+2M]      pbest    1 MB
    //   [+1M]      pidx     1 MB
    float2* W = (float2*)ws;
    float* qt = (float*)(ws + 32768);
    _Float16* a2 = (_Float16*)(ws + 32768);
    H2* u2 = (H2*)(ws + 32768 + (size_t)67108864);
    _Float16* b2 = (_Float16*)(ws + 32768 + (size_t)67108864 * 2);
    float* pbest = (float*)(ws + 32768 + (size_t)67108864 * 2 + 2097152);
    int* pidx = (int*)(ws + 32768 + (size_t)67108864 * 2 + 2097152 + 1048576);

    hipLaunchKernelGGL(twiddle_init, dim3(16), dim3(256), 0, stream, W);
    hipLaunchKernelGGL(transpose_kernel, dim3(128, 16, 8), dim3(32, 8, 1), 0,
                       stream, q, qt);
    hipLaunchKernelGGL(fft_phase_kernel, dim3(2048), dim3(256), 0, stream,
                       qt, u2, W);
    hipLaunchKernelGGL(abuild_kernel, dim3(64, 8, 8), dim3(256), 0, stream,
                       u2, a2);
    hipLaunchKernelGGL(bbuild_kernel, dim3(512), dim3(256), 0, stream,
                       items, b2);
    hipLaunchKernelGGL(gemm_mfma_argmax, dim3(8, 256), dim3(256), 0, stream,
                       a2, b2, pbest, pidx);
    hipLaunchKernelGGL(combine_loss_kernel, dim3(NROWS / 4), dim3(256), 0,
                       stream, q, items, pbest, pidx, out);
}

// Round 6
// 400.895 us; speedup vs baseline: 1.9093x; 1.1640x over previous
//
#include <hip/hip_runtime.h>

// ---------------------------------------------------------------------------
// GatheringLoss: phase-only FFT reconstruction -> dense score -> top-1 -> SSE
// queries: (8, 4096, 512) f32, items: (1024, 512) f32, out: (8, 4096) f32
// unit = irfft(exp(-1j*angle(rfft(q)))) == real(FFT(X/|X|))/N, X = FFT(q).
// Score GEMM on MFMA f16 with exact 2-way split (3 products, lo*lo omitted;
// operands pre-scaled by 2^10 -> argmax invariant).
// ---------------------------------------------------------------------------

#define NB 8
#define NS 4096
#define NF 512
#define NK 1024
#define NROWS (NB * NS)      // 32768
#define NKB 8                // n-chunks of 128
#define KK 1024              // row length in halves ([hi(512) | lo(512)])
#define APITCH 80            // LDS row pitch (64 B data + 16 pad -> 2-way banks)

// LDS bank-derotation for the FFT buffers.
#define SWZ(i) ((((i) & ~15)) | (((i) + 5 * ((i) >> 4)) & 15))

typedef _Float16 half8 __attribute__((ext_vector_type(8)));
typedef float floatx4 __attribute__((ext_vector_type(4)));
struct H2 { _Float16 x, y; };   // (hi, lo)

__device__ __forceinline__ float2 cmulf(float2 a, float2 b) {
    return make_float2(a.x * b.x - a.y * b.y, a.x * b.y + a.y * b.x);
}

__device__ __forceinline__ float2 unitize(float2 v) {
    float m2 = v.x * v.x + v.y * v.y;
    if (m2 > 0.f) {
        float inv = 1.0f / sqrtf(m2);
        return make_float2(v.x * inv, v.y * inv);
    }
    return make_float2(1.f, 0.f);
}

__device__ __forceinline__ H2 split_h2(float v) {
    _Float16 h = (_Float16)v;
    float lo = v - (float)h;
    H2 r; r.x = h; r.y = (_Float16)lo; return r;
}

// ---------------------------------------------------------------------------
// Kernel 1: twiddle table
// ---------------------------------------------------------------------------
__global__ void twiddle_init(float2* __restrict__ W) {
    int k = blockIdx.x * 256 + threadIdx.x;
    double ang = -2.0 * 3.14159265358979323846 * (double)k / 4096.0;
    W[k] = make_float2((float)cos(ang), (float)sin(ang));
}

// ---------------------------------------------------------------------------
// Kernel 2: transpose (b, s, f) -> (b, f, s) fp32
// ---------------------------------------------------------------------------
__global__ __launch_bounds__(256) void transpose_kernel(
        const float* __restrict__ q, float* __restrict__ qt) {
    __shared__ float tile[32][33];
    int b = blockIdx.z;
    int s0 = blockIdx.x * 32;
    int f0 = blockIdx.y * 32;
    int tx = threadIdx.x;
    int ty = threadIdx.y;
    const float* qb = q + (size_t)b * NS * NF;
    float* qtb = qt + (size_t)b * NF * NS;
#pragma unroll
    for (int i = 0; i < 4; ++i) {
        int s = s0 + ty + i * 8;
        tile[ty + i * 8][tx] = qb[(size_t)s * NF + f0 + tx];
    }
    __syncthreads();
#pragma unroll
    for (int i = 0; i < 4; ++i) {
        int f = f0 + ty + i * 8;
        qtb[(size_t)f * NS + s0 + tx] = tile[tx][ty + i * 8];
    }
}

// ---------------------------------------------------------------------------
// Radix-4 Stockham 4096-pt FFT, 6 stages, 256 threads. Result back in A.
// ---------------------------------------------------------------------------
__device__ __forceinline__ void fft4096(float2* A, float2* B,
                                        const float2* __restrict__ W, int t) {
    float2* src = A;
    float2* dst = B;
#pragma unroll
    for (int st = 0; st < 6; ++st) {
        const int s = 1 << (2 * st);
        __syncthreads();
#pragma unroll
        for (int j = 0; j < 4; ++j) {
            int bi = t + j * 256;
            float2 a = src[SWZ(bi)];
            float2 b = src[SWZ(bi + 1024)];
            float2 c = src[SWZ(bi + 2048)];
            float2 d = src[SWZ(bi + 3072)];
            float2 apc = make_float2(a.x + c.x, a.y + c.y);
            float2 amc = make_float2(a.x - c.x, a.y - c.y);
            float2 bpd = make_float2(b.x + d.x, b.y + d.y);
            float2 bmd = make_float2(b.x - d.x, b.y - d.y);
            float2 x0 = make_float2(apc.x + bpd.x, apc.y + bpd.y);
            float2 x1 = make_float2(amc.x + bmd.y, amc.y - bmd.x);
            float2 x2 = make_float2(apc.x - bpd.x, apc.y - bpd.y);
            float2 x3 = make_float2(amc.x - bmd.y, amc.y + bmd.x);
            int q = bi & (s - 1);
            int pw = bi - q;
            int dbase = 4 * bi - 3 * q;
            float2 w1 = W[pw & 4095];
            float2 w2 = W[(2 * pw) & 4095];
            float2 w3 = W[(3 * pw) & 4095];
            dst[SWZ(dbase)] = x0;
            dst[SWZ(dbase + s)] = cmulf(w1, x1);
            dst[SWZ(dbase + 2 * s)] = cmulf(w2, x2);
            dst[SWZ(dbase + 3 * s)] = cmulf(w3, x3);
        }
        float2* tmp = src; src = dst; dst = tmp;
    }
}

// ---------------------------------------------------------------------------
// Kernel 3: two rows per block; epilogue emits scaled fp16 (hi,lo) splits.
// U2 layout: [flat_row = b*512+f][s] of H2.  a' = 1024*unit = Re(F)*0.25.
// ---------------------------------------------------------------------------
__global__ __launch_bounds__(256) void fft_phase_kernel(
        const float* __restrict__ qt, H2* __restrict__ u2,
        const float2* __restrict__ W) {
    __shared__ float2 bufA[4096];
    __shared__ float2 bufB[4096];
    const int t = threadIdx.x;
    const float* x0 = qt + (size_t)(2 * blockIdx.x) * NS;
    const float* x1 = x0 + NS;

    const float4* a4 = (const float4*)x0;
    const float4* b4 = (const float4*)x1;
#pragma unroll
    for (int i = 0; i < 4; ++i) {
        int idx = t + i * 256;
        float4 va = a4[idx];
        float4 vb = b4[idx];
        bufA[SWZ(idx * 4 + 0)] = make_float2(va.x, vb.x);
        bufA[SWZ(idx * 4 + 1)] = make_float2(va.y, vb.y);
        bufA[SWZ(idx * 4 + 2)] = make_float2(va.z, vb.z);
        bufA[SWZ(idx * 4 + 3)] = make_float2(va.w, vb.w);
    }

    fft4096(bufA, bufB, W, t);          // Z = FFT(x0 + i*x1)
    __syncthreads();

#pragma unroll
    for (int j = 0; j < 8; ++j) {
        int k = t + j * 256;            // 0..2047
        if (k == 0) {
            float2 z0 = bufA[SWZ(0)];
            float2 zh = bufA[SWZ(2048)];
            float2 u00 = unitize(make_float2(z0.x, 0.f));
            float2 u10 = unitize(make_float2(z0.y, 0.f));
            bufA[SWZ(0)] = make_float2(u00.x, u10.x);
            float2 u0h = unitize(make_float2(zh.x, 0.f));
            float2 u1h = unitize(make_float2(zh.y, 0.f));
            bufA[SWZ(2048)] = make_float2(u0h.x, u1h.x);
        } else {
            float2 zk = bufA[SWZ(k)];
            float2 zm = bufA[SWZ(4096 - k)];
            float2 a = make_float2(0.5f * (zk.x + zm.x), 0.5f * (zk.y - zm.y));
            float2 bq = make_float2(0.5f * (zk.x - zm.x), 0.5f * (zk.y + zm.y));
            float2 x1k = make_float2(bq.y, -bq.x);
            float2 u0 = unitize(a);
            float2 u1 = unitize(x1k);
            bufA[SWZ(k)] = make_float2(u0.x - u1.y, u0.y + u1.x);
            bufA[SWZ(4096 - k)] = make_float2(u0.x + u1.y, u1.x - u0.y);
        }
    }

    fft4096(bufA, bufB, W, t);          // F = FFT(V) = u0*N + i*u1*N
    __syncthreads();

    H2* o0 = u2 + (size_t)(2 * blockIdx.x) * NS;
    H2* o1 = o0 + NS;
    const float c = 0.25f;              // (1/4096) * 1024
#pragma unroll
    for (int i = 0; i < 4; ++i) {
        int idx = t + i * 256;
        H2 t0[4], t1[4];
#pragma unroll
        for (int k = 0; k < 4; ++k) {
            float2 e = bufA[SWZ(idx * 4 + k)];
            t0[k] = split_h2(e.x * c);
            t1[k] = split_h2(e.y * c);
        }
        *(float4*)&o0[idx * 4] = *(float4*)t0;
        *(float4*)&o1[idx * 4] = *(float4*)t1;
    }
}

// ---------------------------------------------------------------------------
// Kernel 4: A''-builder: U2 [f][s] (H2) -> A'' [row=b*4096+s][ Ahi | Alo ]
// ---------------------------------------------------------------------------
__global__ __launch_bounds__(256) void abuild_kernel(
        const H2* __restrict__ u2, _Float16* __restrict__ a2) {
    __shared__ H2 tile[64][65];
    const int b = blockIdx.z;
    const int f0 = blockIdx.y * 64;
    const int s0 = blockIdx.x * 64;
    const int t = threadIdx.x;
    const int fr = t >> 6;        // 0..3
    const int sc = t & 63;
#pragma unroll
    for (int i = 0; i < 16; ++i) {
        int f = fr + i * 4;
        tile[f][sc] = u2[(size_t)(b * NF + f0 + f) * NS + s0 + sc];
    }
    __syncthreads();
    const int s = t >> 2;         // 0..63
    const int qd = t & 3;         // 0..3 -> f block of 16
    _Float16 xs[16], ys[16];
#pragma unroll
    for (int j = 0; j < 16; ++j) {
        H2 v = tile[qd * 16 + j][s];
        xs[j] = v.x;
        ys[j] = v.y;
    }
    size_t rowoff = ((size_t)(b * NS + s0 + s)) * KK;
    _Float16* pr = a2 + rowoff + (f0 + qd * 16);
    *(float4*)&pr[0] = ((float4*)xs)[0];
    *(float4*)&pr[8] = ((float4*)xs)[1];
    _Float16* pl = pr + 512;
    *(float4*)&pl[0] = ((float4*)ys)[0];
    *(float4*)&pl[8] = ((float4*)ys)[1];
}

// ---------------------------------------------------------------------------
// Kernel 5: B''-builder: items [n][f] f32 -> B'' [n][ Bhi(512) | Blo(512) ]
// ---------------------------------------------------------------------------
__global__ __launch_bounds__(256) void bbuild_kernel(
        const float* __restrict__ items, _Float16* __restrict__ b2) {
    int id = blockIdx.x * 256 + threadIdx.x;   // 1024*128
    int n = id >> 7, fq = id & 127;
    float4 v = *(const float4*)&items[(size_t)n * NF + fq * 4];
    H2 h0 = split_h2(v.x * 1024.f);
    H2 h1 = split_h2(v.y * 1024.f);
    H2 h2v = split_h2(v.z * 1024.f);
    H2 h3 = split_h2(v.w * 1024.f);
    _Float16 hs[4] = {h0.x, h1.x, h2v.x, h3.x};
    _Float16 ls[4] = {h0.y, h1.y, h2v.y, h3.y};
    _Float16* pr = b2 + (size_t)n * KK + fq * 4;
    *(float2*)pr = *(float2*)hs;
    *(float2*)(pr + 512) = *(float2*)ls;
}

// ---------------------------------------------------------------------------
// Kernel 6: MFMA score GEMM + fused per-(row, n-chunk) argmax.
// Block 128 rows x 128 n, 4 waves (2x2), per-wave 64x64 = 4x4 MFMA frags.
// Shared-operand chunks: per 32-half chunk stage {Ahi,Alo,Bhi,Blo}, fire
// Ahi*Bhi + Alo*Bhi + Ahi*Blo into the same acc (48 MFMA / 16 ds_read).
// Double-buffered LDS (2 x 40 KB), reg-staged, ONE barrier per chunk; next
// chunk's global loads issued right after the barrier (overlap with MFMA).
// Grid (256, 8): sb fastest -> all 8 kb-blocks of a panel on one XCD.
// ---------------------------------------------------------------------------
__global__ __launch_bounds__(256, 2) void gemm_mfma_argmax(
        const _Float16* __restrict__ a2, const _Float16* __restrict__ b2,
        float* __restrict__ pbest, int* __restrict__ pidx) {
    __shared__ __align__(16) char smem[2 * 4 * 128 * APITCH];   // 80 KB
    const int sb = blockIdx.x;      // 0..255
    const int kb = blockIdx.y;      // 0..7
    const int row0 = sb * 128;
    const int n0 = kb * 128;
    const int t = threadIdx.x;
    const int wid = t >> 6, l = t & 63, g = l >> 4, c = l & 15;
    const int wr = wid >> 1, wc = wid & 1;

    floatx4 acc[4][4];
#pragma unroll
    for (int m = 0; m < 4; ++m)
#pragma unroll
        for (int n = 0; n < 4; ++n) acc[m][n] = (floatx4)0.f;

    const int r = t >> 1, h = t & 1;
    // global row pointers (halves); chunk ch adds ch*32
    const _Float16* gA = a2 + (size_t)(row0 + r) * KK + h * 16;
    const _Float16* gB = b2 + (size_t)(n0 + r) * KK + h * 16;
    const int woff = r * APITCH + h * 32;          // byte offset within tile

#define TILE(buf, tl) (smem + (size_t)((buf) * 4 + (tl)) * 128 * APITCH)

    float4 rAh0, rAh1, rAl0, rAl1, rBh0, rBh1, rBl0, rBl1;
#define LOADCH(ch)                                                          \
    {                                                                       \
        const _Float16* pa = gA + (ch) * 32;                                \
        rAh0 = *(const float4*)(pa);                                        \
        rAh1 = *(const float4*)(pa + 8);                                    \
        rAl0 = *(const float4*)(pa + 512);                                  \
        rAl1 = *(const float4*)(pa + 520);                                  \
        const _Float16* pb = gB + (ch) * 32;                                \
        rBh0 = *(const float4*)(pb);                                        \
        rBh1 = *(const float4*)(pb + 8);                                    \
        rBl0 = *(const float4*)(pb + 512);                                  \
        rBl1 = *(const float4*)(pb + 520);                                  \
    }

    LOADCH(0);
    int cur = 0;
    for (int ch = 0; ch < 16; ++ch) {
        // write staged regs to buf[cur]
        *(float4*)(TILE(cur, 0) + woff) = rAh0;
        *(float4*)(TILE(cur, 0) + woff + 16) = rAh1;
        *(float4*)(TILE(cur, 1) + woff) = rAl0;
        *(float4*)(TILE(cur, 1) + woff + 16) = rAl1;
        *(float4*)(TILE(cur, 2) + woff) = rBh0;
        *(float4*)(TILE(cur, 2) + woff + 16) = rBh1;
        *(float4*)(TILE(cur, 3) + woff) = rBl0;
        *(float4*)(TILE(cur, 3) + woff + 16) = rBl1;
        __syncthreads();
        if (ch < 15) LOADCH(ch + 1);    // overlaps with MFMA below
        {
            const char* Ah = TILE(cur, 0);
            const char* Al = TILE(cur, 1);
            const char* Bh = TILE(cur, 2);
            const char* Bl = TILE(cur, 3);
            half8 afh[4], afl[4], bfh[4], bfl[4];
#pragma unroll
            for (int m = 0; m < 4; ++m) {
                int ro = (wr * 64 + m * 16 + c) * APITCH + g * 16;
                afh[m] = *(const half8*)(Ah + ro);
                afl[m] = *(const half8*)(Al + ro);
            }
#pragma unroll
            for (int n = 0; n < 4; ++n) {
                int ro = (wc * 64 + n * 16 + c) * APITCH + g * 16;
                bfh[n] = *(const half8*)(Bh + ro);
                bfl[n] = *(const half8*)(Bl + ro);
            }
#pragma unroll
            for (int m = 0; m < 4; ++m)
#pragma unroll
                for (int n = 0; n < 4; ++n) {
                    acc[m][n] = __builtin_amdgcn_mfma_f32_16x16x32_f16(
                        afh[m], bfh[n], acc[m][n], 0, 0, 0);
                    acc[m][n] = __builtin_amdgcn_mfma_f32_16x16x32_f16(
                        afl[m], bfh[n], acc[m][n], 0, 0, 0);
                    acc[m][n] = __builtin_amdgcn_mfma_f32_16x16x32_f16(
                        afh[m], bfl[n], acc[m][n], 0, 0, 0);
                }
        }
        cur ^= 1;
    }
#undef LOADCH
#undef TILE

    __syncthreads();
    float* cand = (float*)smem;            // [2][128]
    int* candi = (int*)(smem + 1024);      // [2][128]

#pragma unroll
    for (int m = 0; m < 4; ++m) {
#pragma unroll
        for (int rr = 0; rr < 4; ++rr) {
            float best = acc[m][0][rr];
            int bi = c;                    // n-frag 0, col c
#pragma unroll
            for (int n = 1; n < 4; ++n) {
                float v = acc[m][n][rr];
                int ig = n * 16 + c;
                if (v > best) { best = v; bi = ig; }
            }
#pragma unroll
            for (int off = 1; off < 16; off <<= 1) {
                float ov = __shfl_xor(best, off);
                int oi = __shfl_xor(bi, off);
                if (ov > best || (ov == best && oi < bi)) { best = ov; bi = oi; }
            }
            if (c == 0) {
                int s_local = wr * 64 + m * 16 + 4 * g + rr;
                cand[wc * 128 + s_local] = best;
                candi[wc * 128 + s_local] = bi;   // 0..63 within wave n-slice
            }
        }
    }
    __syncthreads();
    if (t < 128) {
        float b0v = cand[t];
        int b0i = candi[t];
        float b1v = cand[128 + t];
        int b1i = candi[128 + t] + 64;
        float best = b0v; int bi = b0i;
        if (b1v > b0v) { best = b1v; bi = b1i; }   // tie keeps lower (wc=0)
        int row = row0 + t;
        pbest[(size_t)row * NKB + kb] = best;
        pidx[(size_t)row * NKB + kb] = n0 + bi;
    }
}

// ---------------------------------------------------------------------------
// Kernel 7: combine partials (ascending n-chunk, strict >) + SSE vs queries
// ---------------------------------------------------------------------------
__global__ __launch_bounds__(256) void combine_loss_kernel(
        const float* __restrict__ q, const float* __restrict__ items,
        const float* __restrict__ pbest, const int* __restrict__ pidx,
        float* __restrict__ out) {
    const int wid = threadIdx.x >> 6;
    const int lane = threadIdx.x & 63;
    const int row = blockIdx.x * 4 + wid;

    float best = pbest[(size_t)row * NKB];
    int bidx = pidx[(size_t)row * NKB];
#pragma unroll
    for (int g = 1; g < NKB; ++g) {
        float v = pbest[(size_t)row * NKB + g];
        if (v > best) { best = v; bidx = pidx[(size_t)row * NKB + g]; }
    }

    const float4* qr = (const float4*)(q + (size_t)row * NF);
    const float4* mr = (const float4*)(items + (size_t)bidx * NF);
    float sum = 0.f;
#pragma unroll
    for (int i = 0; i < 2; ++i) {
        float4 a = qr[lane + i * 64];
        float4 m = mr[lane + i * 64];
        float dx = a.x - m.x, dy = a.y - m.y, dz = a.z - m.z, dw = a.w - m.w;
        sum += dx * dx + dy * dy + dz * dz + dw * dw;
    }
#pragma unroll
    for (int off = 32; off; off >>= 1) sum += __shfl_down(sum, off, 64);
    if (lane == 0) out[row] = sum;
}

// ---------------------------------------------------------------------------
extern "C" void kernel_launch(void* const* d_in, const int* in_sizes, int n_in,
                              void* d_out, int out_size, void* d_ws, size_t ws_size,
                              hipStream_t stream) {
    const float* q = (const float*)d_in[0];
    const float* items = (const float*)d_in[1];
    float* out = (float*)d_out;

    char* ws = (char*)d_ws;
    // Layout (132.1 MB total):
    //   [0]        W       32 KB
    //   [32K]      qt/A''  64 MB   (fp32 qt for FFT, then overwritten by A'')
    //   [32K+64M]  U2      64 MB   (H2 [4096][4096])
    //   [+64M]     B''      2 MB
    //   [+2M]      pbest    1 MB
    //   [+1M]      pidx     1 MB
    float2* W = (float2*)ws;
    float* qt = (float*)(ws + 32768);
    _Float16* a2 = (_Float16*)(ws + 32768);
    H2* u2 = (H2*)(ws + 32768 + (size_t)67108864);
    _Float16* b2 = (_Float16*)(ws + 32768 + (size_t)67108864 * 2);
    float* pbest = (float*)(ws + 32768 + (size_t)67108864 * 2 + 2097152);
    int* pidx = (int*)(ws + 32768 + (size_t)67108864 * 2 + 2097152 + 1048576);

    hipLaunchKernelGGL(twiddle_init, dim3(16), dim3(256), 0, stream, W);
    hipLaunchKernelGGL(transpose_kernel, dim3(128, 16, 8), dim3(32, 8, 1), 0,
                       stream, q, qt);
    hipLaunchKernelGGL(fft_phase_kernel, dim3(2048), dim3(256), 0, stream,
                       qt, u2, W);
    hipLaunchKernelGGL(abuild_kernel, dim3(64, 8, 8), dim3(256), 0, stream,
                       u2, a2);
    hipLaunchKernelGGL(bbuild_kernel, dim3(512), dim3(256), 0, stream,
                       items, b2);
    hipLaunchKernelGGL(gemm_mfma_argmax, dim3(256, 8), dim3(256), 0, stream,
                       a2, b2, pbest, pidx);
    hipLaunchKernelGGL(combine_loss_kernel, dim3(NROWS / 4), dim3(256), 0,
                       stream, q, items, pbest, pidx, out);
}

// Round 7
// 320.166 us; speedup vs baseline: 2.3907x; 1.2521x over previous
//
#include <hip/hip_runtime.h>

// ---------------------------------------------------------------------------
// GatheringLoss: phase-only FFT reconstruction -> dense score -> top-1 -> SSE
// queries: (8, 4096, 512) f32, items: (1024, 512) f32, out: (8, 4096) f32
// unit = irfft(exp(-1j*angle(rfft(q)))) == real(FFT(X/|X|))/N, X = FFT(q).
// Score GEMM on MFMA f16 with exact 2-way split (3 products, lo*lo omitted;
// operands pre-scaled by 2^10 -> argmax invariant).
// ---------------------------------------------------------------------------

#define NB 8
#define NS 4096
#define NF 512
#define NK 1024
#define NROWS (NB * NS)      // 32768
#define NKB 8                // n-chunks of 128
#define KK 1024              // row length in halves ([hi(512) | lo(512)])

// FFT LDS swizzle: spreads stage-0 scatter (i=16t+j) across banks; keeps
// stride-256 reads and stage-1/2 writes conflict-free (enumerated).
#define SWZF(i) ((i) ^ (((i) >> 4) & 15))

typedef _Float16 half8 __attribute__((ext_vector_type(8)));
typedef float floatx4 __attribute__((ext_vector_type(4)));
struct H2 { _Float16 x, y; };   // (hi, lo)

__device__ __forceinline__ float2 cmulf(float2 a, float2 b) {
    return make_float2(a.x * b.x - a.y * b.y, a.x * b.y + a.y * b.x);
}

__device__ __forceinline__ float2 unitize(float2 v) {
    float m2 = v.x * v.x + v.y * v.y;
    if (m2 > 0.f) {
        float inv = 1.0f / sqrtf(m2);
        return make_float2(v.x * inv, v.y * inv);
    }
    return make_float2(1.f, 0.f);
}

__device__ __forceinline__ H2 split_h2(float v) {
    _Float16 h = (_Float16)v;
    float lo = v - (float)h;
    H2 r; r.x = h; r.y = (_Float16)lo; return r;
}

// o[k] = sum_n in[n] * (-i)^(n*k)
__device__ __forceinline__ void dft4(float2 a, float2 b, float2 c, float2 d,
                                     float2& o0, float2& o1, float2& o2, float2& o3) {
    float2 apc = make_float2(a.x + c.x, a.y + c.y);
    float2 amc = make_float2(a.x - c.x, a.y - c.y);
    float2 bpd = make_float2(b.x + d.x, b.y + d.y);
    float2 bmd = make_float2(b.x - d.x, b.y - d.y);
    o0 = make_float2(apc.x + bpd.x, apc.y + bpd.y);
    o1 = make_float2(amc.x + bmd.y, amc.y - bmd.x);   // amc - i*bmd
    o2 = make_float2(apc.x - bpd.x, apc.y - bpd.y);
    o3 = make_float2(amc.x - bmd.y, amc.y + bmd.x);   // amc + i*bmd
}

// ---------------------------------------------------------------------------
// Kernel 1: twiddle table W[k] = exp(-2*pi*i*k/4096), fp64-computed
// ---------------------------------------------------------------------------
__global__ void twiddle_init(float2* __restrict__ W) {
    int k = blockIdx.x * 256 + threadIdx.x;
    double ang = -2.0 * 3.14159265358979323846 * (double)k / 4096.0;
    W[k] = make_float2((float)cos(ang), (float)sin(ang));
}

// ---------------------------------------------------------------------------
// Kernel 2: transpose (b, s, f) -> (b, f, s) fp32
// ---------------------------------------------------------------------------
__global__ __launch_bounds__(256) void transpose_kernel(
        const float* __restrict__ q, float* __restrict__ qt) {
    __shared__ float tile[32][33];
    int b = blockIdx.z;
    int s0 = blockIdx.x * 32;
    int f0 = blockIdx.y * 32;
    int tx = threadIdx.x;
    int ty = threadIdx.y;
    const float* qb = q + (size_t)b * NS * NF;
    float* qtb = qt + (size_t)b * NF * NS;
#pragma unroll
    for (int i = 0; i < 4; ++i) {
        int s = s0 + ty + i * 8;
        tile[ty + i * 8][tx] = qb[(size_t)s * NF + f0 + tx];
    }
    __syncthreads();
#pragma unroll
    for (int i = 0; i < 4; ++i) {
        int f = f0 + ty + i * 8;
        qtb[(size_t)f * NS + s0 + tx] = tile[tx][ty + i * 8];
    }
}

// ---------------------------------------------------------------------------
// Radix-16 Stockham 4096-pt FFT: 3 stages (s = 1, 16, 256), 256 threads,
// one in-register DFT16 per thread per stage. A->B, B->A, A->B: result in B.
// dst base = 16*bi - 15*q (q = bi mod s); stage twiddle W^(j*(bi-q)); last
// stage twiddle-free (bi-q == 0).
// ---------------------------------------------------------------------------
__device__ __forceinline__ void fft4096_r16(float2* A, float2* B,
                                            const float2* __restrict__ W, int t) {
    const float C1 = 0.92387953251128674f;   // cos(pi/8)
    const float S1 = 0.38268343236508978f;   // sin(pi/8)
    const float R2 = 0.70710678118654752f;
    const float2 w1 = make_float2(C1, -S1);
    const float2 w2 = make_float2(R2, -R2);
    const float2 w3 = make_float2(S1, -C1);
    const float2 w4 = make_float2(0.f, -1.f);
    const float2 w6 = make_float2(-R2, -R2);
    const float2 w9 = make_float2(-C1, S1);
#pragma unroll
    for (int st = 0; st < 3; ++st) {
        float2* src = (st == 1) ? B : A;
        float2* dst = (st == 1) ? A : B;
        const int s = (st == 0) ? 1 : (st == 1) ? 16 : 256;
        __syncthreads();
        float2 x[16];
#pragma unroll
        for (int j = 0; j < 16; ++j) x[j] = src[SWZF(t + j * 256)];
        // DFT16: out[4*k1+k0] = sum_{n0} w16^{n0*k0} (sum_{n1} x[4n1+n0] w4^{n1*k0}) w4^{n0*k1}
        float2 y[4][4];   // y[n0][k0]
#pragma unroll
        for (int n0 = 0; n0 < 4; ++n0)
            dft4(x[n0], x[4 + n0], x[8 + n0], x[12 + n0],
                 y[n0][0], y[n0][1], y[n0][2], y[n0][3]);
        y[1][1] = cmulf(w1, y[1][1]);
        y[1][2] = cmulf(w2, y[1][2]);
        y[1][3] = cmulf(w3, y[1][3]);
        y[2][1] = cmulf(w2, y[2][1]);
        y[2][2] = cmulf(w4, y[2][2]);
        y[2][3] = cmulf(w6, y[2][3]);
        y[3][1] = cmulf(w3, y[3][1]);
        y[3][2] = cmulf(w6, y[3][2]);
        y[3][3] = cmulf(w9, y[3][3]);
        float2 z[16];
#pragma unroll
        for (int k0 = 0; k0 < 4; ++k0)
            dft4(y[0][k0], y[1][k0], y[2][k0], y[3][k0],
                 z[k0], z[4 + k0], z[8 + k0], z[12 + k0]);
        const int q = t & (s - 1);
        const int pw = t - q;
        const int dbase = 16 * t - 15 * q;
        dst[SWZF(dbase)] = z[0];
        if (st == 2) {
#pragma unroll
            for (int j = 1; j < 16; ++j)
                dst[SWZF(dbase + j * s)] = z[j];
        } else {
#pragma unroll
            for (int j = 1; j < 16; ++j)
                dst[SWZF(dbase + j * s)] = cmulf(W[(j * pw) & 4095], z[j]);
        }
    }
}

// ---------------------------------------------------------------------------
// Kernel 3: two rows per block (two-for-one real FFT both directions);
// epilogue emits scaled fp16 (hi,lo) splits into U2 [b*512+f][s].
// ---------------------------------------------------------------------------
__global__ __launch_bounds__(256) void fft_phase_kernel(
        const float* __restrict__ qt, H2* __restrict__ u2,
        const float2* __restrict__ W) {
    __shared__ float2 bufA[4096];
    __shared__ float2 bufB[4096];
    const int t = threadIdx.x;
    const float* x0 = qt + (size_t)(2 * blockIdx.x) * NS;
    const float* x1 = x0 + NS;

    const float4* a4 = (const float4*)x0;
    const float4* b4 = (const float4*)x1;
#pragma unroll
    for (int i = 0; i < 4; ++i) {
        int idx = t + i * 256;
        float4 va = a4[idx];
        float4 vb = b4[idx];
        bufA[SWZF(idx * 4 + 0)] = make_float2(va.x, vb.x);
        bufA[SWZF(idx * 4 + 1)] = make_float2(va.y, vb.y);
        bufA[SWZF(idx * 4 + 2)] = make_float2(va.z, vb.z);
        bufA[SWZF(idx * 4 + 3)] = make_float2(va.w, vb.w);
    }

    fft4096_r16(bufA, bufB, W, t);      // Z = FFT(x0 + i*x1) in bufB
    __syncthreads();

    // Unpack X0, X1; normalize; repack V = U0 + i*U1 (both Hermitian).
#pragma unroll
    for (int j = 0; j < 8; ++j) {
        int k = t + j * 256;            // 0..2047
        if (k == 0) {
            float2 z0 = bufB[SWZF(0)];
            float2 zh = bufB[SWZF(2048)];
            float2 u00 = unitize(make_float2(z0.x, 0.f));
            float2 u10 = unitize(make_float2(z0.y, 0.f));
            bufB[SWZF(0)] = make_float2(u00.x, u10.x);
            float2 u0h = unitize(make_float2(zh.x, 0.f));
            float2 u1h = unitize(make_float2(zh.y, 0.f));
            bufB[SWZF(2048)] = make_float2(u0h.x, u1h.x);
        } else {
            float2 zk = bufB[SWZF(k)];
            float2 zm = bufB[SWZF(4096 - k)];
            float2 a = make_float2(0.5f * (zk.x + zm.x), 0.5f * (zk.y - zm.y));
            float2 bq = make_float2(0.5f * (zk.x - zm.x), 0.5f * (zk.y + zm.y));
            float2 x1k = make_float2(bq.y, -bq.x);
            float2 u0 = unitize(a);
            float2 u1 = unitize(x1k);
            bufB[SWZF(k)] = make_float2(u0.x - u1.y, u0.y + u1.x);
            bufB[SWZF(4096 - k)] = make_float2(u0.x + u1.y, u1.x - u0.y);
        }
    }

    fft4096_r16(bufB, bufA, W, t);      // F = FFT(V) in bufA
    __syncthreads();

    H2* o0 = u2 + (size_t)(2 * blockIdx.x) * NS;
    H2* o1 = o0 + NS;
    const float c = 0.25f;              // (1/4096) * 1024
#pragma unroll
    for (int i = 0; i < 4; ++i) {
        int idx = t + i * 256;
        H2 t0[4], t1[4];
#pragma unroll
        for (int k = 0; k < 4; ++k) {
            float2 e = bufA[SWZF(idx * 4 + k)];
            t0[k] = split_h2(e.x * c);
            t1[k] = split_h2(e.y * c);
        }
        *(float4*)&o0[idx * 4] = *(float4*)t0;
        *(float4*)&o1[idx * 4] = *(float4*)t1;
    }
}

// ---------------------------------------------------------------------------
// Kernel 4: A''-builder: U2 [f][s] (H2) -> A'' [row=b*4096+s][ Ahi | Alo ]
// ---------------------------------------------------------------------------
__global__ __launch_bounds__(256) void abuild_kernel(
        const H2* __restrict__ u2, _Float16* __restrict__ a2) {
    __shared__ H2 tile[64][65];
    const int b = blockIdx.z;
    const int f0 = blockIdx.y * 64;
    const int s0 = blockIdx.x * 64;
    const int t = threadIdx.x;
    const int fr = t >> 6;        // 0..3
    const int sc = t & 63;
#pragma unroll
    for (int i = 0; i < 16; ++i) {
        int f = fr + i * 4;
        tile[f][sc] = u2[(size_t)(b * NF + f0 + f) * NS + s0 + sc];
    }
    __syncthreads();
    const int s = t >> 2;         // 0..63
    const int qd = t & 3;         // 0..3 -> f block of 16
    _Float16 xs[16], ys[16];
#pragma unroll
    for (int j = 0; j < 16; ++j) {
        H2 v = tile[qd * 16 + j][s];
        xs[j] = v.x;
        ys[j] = v.y;
    }
    size_t rowoff = ((size_t)(b * NS + s0 + s)) * KK;
    _Float16* pr = a2 + rowoff + (f0 + qd * 16);
    *(float4*)&pr[0] = ((float4*)xs)[0];
    *(float4*)&pr[8] = ((float4*)xs)[1];
    _Float16* pl = pr + 512;
    *(float4*)&pl[0] = ((float4*)ys)[0];
    *(float4*)&pl[8] = ((float4*)ys)[1];
}

// ---------------------------------------------------------------------------
// Kernel 5: B''-builder: items [n][f] f32 -> B'' [n][ Bhi(512) | Blo(512) ]
// ---------------------------------------------------------------------------
__global__ __launch_bounds__(256) void bbuild_kernel(
        const float* __restrict__ items, _Float16* __restrict__ b2) {
    int id = blockIdx.x * 256 + threadIdx.x;   // 1024*128
    int n = id >> 7, fq = id & 127;
    float4 v = *(const float4*)&items[(size_t)n * NF + fq * 4];
    H2 h0 = split_h2(v.x * 1024.f);
    H2 h1 = split_h2(v.y * 1024.f);
    H2 h2v = split_h2(v.z * 1024.f);
    H2 h3 = split_h2(v.w * 1024.f);
    _Float16 hs[4] = {h0.x, h1.x, h2v.x, h3.x};
    _Float16 ls[4] = {h0.y, h1.y, h2v.y, h3.y};
    _Float16* pr = b2 + (size_t)n * KK + fq * 4;
    *(float2*)pr = *(float2*)hs;
    *(float2*)(pr + 512) = *(float2*)ls;
}

// ---------------------------------------------------------------------------
// Kernel 6: MFMA score GEMM + fused per-(row, n-chunk) argmax.
// Block 128 rows x 128 n, 4 waves (2x2), per-wave 64x64 = 4x4 MFMA frags.
// Per 32-half chunk stage {Ahi,Alo,Bhi,Blo}, fire Ahi*Bhi + Alo*Bhi + Ahi*Blo
// into the same acc (48 MFMA / 16 ds_read). Double-buffered LDS (2 x 32 KB),
// reg-staged, ONE barrier per chunk.
// LDS layout: row stride 64 B, 16B-slot j of row r at ((j ^ ((r>>1)&3))<<4)
// -> frag reads and staging writes both 2-way (free).  2 blocks/CU.
// Grid (256, 8): sb fastest -> all 8 kb-blocks of a panel on one XCD.
// ---------------------------------------------------------------------------
__global__ __launch_bounds__(256, 2) void gemm_mfma_argmax(
        const _Float16* __restrict__ a2, const _Float16* __restrict__ b2,
        float* __restrict__ pbest, int* __restrict__ pidx) {
    __shared__ __align__(16) char smem[2 * 4 * 128 * 64];   // 64 KB
    const int sb = blockIdx.x;      // 0..255
    const int kb = blockIdx.y;      // 0..7
    const int row0 = sb * 128;
    const int n0 = kb * 128;
    const int t = threadIdx.x;
    const int wid = t >> 6, l = t & 63, g = l >> 4, c = l & 15;
    const int wr = wid >> 1, wc = wid & 1;

    floatx4 acc[4][4];
#pragma unroll
    for (int m = 0; m < 4; ++m)
#pragma unroll
        for (int n = 0; n < 4; ++n) acc[m][n] = (floatx4)0.f;

    const int r = t >> 1, h = t & 1;
    const _Float16* gA = a2 + (size_t)(row0 + r) * KK + h * 16;
    const _Float16* gB = b2 + (size_t)(n0 + r) * KK + h * 16;
    const int fsw = (r >> 1) & 3;                  // row swizzle key
    const int w0 = r * 64 + (((2 * h + 0) ^ fsw) << 4);
    const int w1 = r * 64 + (((2 * h + 1) ^ fsw) << 4);

#define TILE(buf, tl) (smem + (size_t)((buf) * 4 + (tl)) * 128 * 64)

    float4 rAh0, rAh1, rAl0, rAl1, rBh0, rBh1, rBl0, rBl1;
#define LOADCH(ch)                                                          \
    {                                                                       \
        const _Float16* pa = gA + (ch) * 32;                                \
        rAh0 = *(const float4*)(pa);                                        \
        rAh1 = *(const float4*)(pa + 8);                                    \
        rAl0 = *(const float4*)(pa + 512);                                  \
        rAl1 = *(const float4*)(pa + 520);                                  \
        const _Float16* pb = gB + (ch) * 32;                                \
        rBh0 = *(const float4*)(pb);                                        \
        rBh1 = *(const float4*)(pb + 8);                                    \
        rBl0 = *(const float4*)(pb + 512);                                  \
        rBl1 = *(const float4*)(pb + 520);                                  \
    }

    LOADCH(0);
    int cur = 0;
    for (int ch = 0; ch < 16; ++ch) {
        *(float4*)(TILE(cur, 0) + w0) = rAh0;
        *(float4*)(TILE(cur, 0) + w1) = rAh1;
        *(float4*)(TILE(cur, 1) + w0) = rAl0;
        *(float4*)(TILE(cur, 1) + w1) = rAl1;
        *(float4*)(TILE(cur, 2) + w0) = rBh0;
        *(float4*)(TILE(cur, 2) + w1) = rBh1;
        *(float4*)(TILE(cur, 3) + w0) = rBl0;
        *(float4*)(TILE(cur, 3) + w1) = rBl1;
        __syncthreads();
        if (ch < 15) LOADCH(ch + 1);    // overlaps with MFMA below
        {
            const char* Ah = TILE(cur, 0);
            const char* Al = TILE(cur, 1);
            const char* Bh = TILE(cur, 2);
            const char* Bl = TILE(cur, 3);
            half8 afh[4], afl[4], bfh[4], bfl[4];
#pragma unroll
            for (int m = 0; m < 4; ++m) {
                int rr = wr * 64 + m * 16 + c;
                int ro = rr * 64 + (((g ^ ((rr >> 1) & 3))) << 4);
                afh[m] = *(const half8*)(Ah + ro);
                afl[m] = *(const half8*)(Al + ro);
            }
#pragma unroll
            for (int n = 0; n < 4; ++n) {
                int rr = wc * 64 + n * 16 + c;
                int ro = rr * 64 + (((g ^ ((rr >> 1) & 3))) << 4);
                bfh[n] = *(const half8*)(Bh + ro);
                bfl[n] = *(const half8*)(Bl + ro);
            }
#pragma unroll
            for (int m = 0; m < 4; ++m)
#pragma unroll
                for (int n = 0; n < 4; ++n) {
                    acc[m][n] = __builtin_amdgcn_mfma_f32_16x16x32_f16(
                        afh[m], bfh[n], acc[m][n], 0, 0, 0);
                    acc[m][n] = __builtin_amdgcn_mfma_f32_16x16x32_f16(
                        afl[m], bfh[n], acc[m][n], 0, 0, 0);
                    acc[m][n] = __builtin_amdgcn_mfma_f32_16x16x32_f16(
                        afh[m], bfl[n], acc[m][n], 0, 0, 0);
                }
        }
        cur ^= 1;
    }
#undef LOADCH
#undef TILE

    __syncthreads();
    float* cand = (float*)smem;            // [2][128]
    int* candi = (int*)(smem + 1024);      // [2][128]

#pragma unroll
    for (int m = 0; m < 4; ++m) {
#pragma unroll
        for (int rr = 0; rr < 4; ++rr) {
            float best = acc[m][0][rr];
            int bi = c;                    // n-frag 0, col c
#pragma unroll
            for (int n = 1; n < 4; ++n) {
                float v = acc[m][n][rr];
                int ig = n * 16 + c;
                if (v > best) { best = v; bi = ig; }
            }
#pragma unroll
            for (int off = 1; off < 16; off <<= 1) {
                float ov = __shfl_xor(best, off);
                int oi = __shfl_xor(bi, off);
                if (ov > best || (ov == best && oi < bi)) { best = ov; bi = oi; }
            }
            if (c == 0) {
                int s_local = wr * 64 + m * 16 + 4 * g + rr;
                cand[wc * 128 + s_local] = best;
                candi[wc * 128 + s_local] = bi;   // 0..63 within wave n-slice
            }
        }
    }
    __syncthreads();
    if (t < 128) {
        float b0v = cand[t];
        int b0i = candi[t];
        float b1v = cand[128 + t];
        int b1i = candi[128 + t] + 64;
        float best = b0v; int bi = b0i;
        if (b1v > b0v) { best = b1v; bi = b1i; }   // tie keeps lower (wc=0)
        int row = row0 + t;
        pbest[(size_t)row * NKB + kb] = best;
        pidx[(size_t)row * NKB + kb] = n0 + bi;
    }
}

// ---------------------------------------------------------------------------
// Kernel 7: combine partials (ascending n-chunk, strict >) + SSE vs queries
// ---------------------------------------------------------------------------
__global__ __launch_bounds__(256) void combine_loss_kernel(
        const float* __restrict__ q, const float* __restrict__ items,
        const float* __restrict__ pbest, const int* __restrict__ pidx,
        float* __restrict__ out) {
    const int wid = threadIdx.x >> 6;
    const int lane = threadIdx.x & 63;
    const int row = blockIdx.x * 4 + wid;

    float best = pbest[(size_t)row * NKB];
    int bidx = pidx[(size_t)row * NKB];
#pragma unroll
    for (int g = 1; g < NKB; ++g) {
        float v = pbest[(size_t)row * NKB + g];
        if (v > best) { best = v; bidx = pidx[(size_t)row * NKB + g]; }
    }

    const float4* qr = (const float4*)(q + (size_t)row * NF);
    const float4* mr = (const float4*)(items + (size_t)bidx * NF);
    float sum = 0.f;
#pragma unroll
    for (int i = 0; i < 2; ++i) {
        float4 a = qr[lane + i * 64];
        float4 m = mr[lane + i * 64];
        float dx = a.x - m.x, dy = a.y - m.y, dz = a.z - m.z, dw = a.w - m.w;
        sum += dx * dx + dy * dy + dz * dz + dw * dw;
    }
#pragma unroll
    for (int off = 32; off; off >>= 1) sum += __shfl_down(sum, off, 64);
    if (lane == 0) out[row] = sum;
}

// ---------------------------------------------------------------------------
extern "C" void kernel_launch(void* const* d_in, const int* in_sizes, int n_in,
                              void* d_out, int out_size, void* d_ws, size_t ws_size,
                              hipStream_t stream) {
    const float* q = (const float*)d_in[0];
    const float* items = (const float*)d_in[1];
    float* out = (float*)d_out;

    char* ws = (char*)d_ws;
    // Layout (132.1 MB total):
    //   [0]        W       32 KB
    //   [32K]      qt/A''  64 MB   (fp32 qt for FFT, then overwritten by A'')
    //   [32K+64M]  U2      64 MB   (H2 [4096][4096])
    //   [+64M]     B''      2 MB
    //   [+2M]      pbest    1 MB
    //   [+1M]      pidx     1 MB
    float2* W = (float2*)ws;
    float* qt = (float*)(ws + 32768);
    _Float16* a2 = (_Float16*)(ws + 32768);
    H2* u2 = (H2*)(ws + 32768 + (size_t)67108864);
    _Float16* b2 = (_Float16*)(ws + 32768 + (size_t)67108864 * 2);
    float* pbest = (float*)(ws + 32768 + (size_t)67108864 * 2 + 2097152);
    int* pidx = (int*)(ws + 32768 + (size_t)67108864 * 2 + 2097152 + 1048576);

    hipLaunchKernelGGL(twiddle_init, dim3(16), dim3(256), 0, stream, W);
    hipLaunchKernelGGL(transpose_kernel, dim3(128, 16, 8), dim3(32, 8, 1), 0,
                       stream, q, qt);
    hipLaunchKernelGGL(fft_phase_kernel, dim3(2048), dim3(256), 0, stream,
                       qt, u2, W);
    hipLaunchKernelGGL(abuild_kernel, dim3(64, 8, 8), dim3(256), 0, stream,
                       u2, a2);
    hipLaunchKernelGGL(bbuild_kernel, dim3(512), dim3(256), 0, stream,
                       items, b2);
    hipLaunchKernelGGL(gemm_mfma_argmax, dim3(256, 8), dim3(256), 0, stream,
                       a2, b2, pbest, pidx);
    hipLaunchKernelGGL(combine_loss_kernel, dim3(NROWS / 4), dim3(256), 0,
                       stream, q, items, pbest, pidx, out);
}

// Round 8
// 314.182 us; speedup vs baseline: 2.4362x; 1.0190x over previous
//
#include <hip/hip_runtime.h>

// ---------------------------------------------------------------------------
// GatheringLoss: phase-only FFT reconstruction -> dense score -> top-1 -> SSE
// queries: (8, 4096, 512) f32, items: (1024, 512) f32, out: (8, 4096) f32
// unit = irfft(exp(-1j*angle(rfft(q)))) == real(FFT(X/|X|))/N, X = FFT(q).
// Score GEMM on MFMA f16, exact 2-way split (3 products, lo*lo omitted;
// operands pre-scaled by 2^10 -> argmax invariant).
// A3/B3 stored FRAGMENT-MAJOR: a wave's MFMA fragment = one coalesced 1 KB
// load -> GEMM has no LDS staging and no barriers in the main loop.
// Layout: elem (row,k) -> halves addr ((row>>4)*32+(k>>5))*512
//         + ((k>>3)&3)*128 + (row&15)*8 + (k&7).
// ---------------------------------------------------------------------------

#define NB 8
#define NS 4096
#define NF 512
#define NK 1024
#define NROWS (NB * NS)      // 32768
#define NKB 8                // n-chunks of 128
#define KK 1024              // row length in halves ([hi(512) | lo(512)])

// FFT LDS swizzle (verified conflict-reducing for radix-16 Stockham).
#define SWZF(i) ((i) ^ (((i) >> 4) & 15))

typedef _Float16 half8 __attribute__((ext_vector_type(8)));
typedef float floatx4 __attribute__((ext_vector_type(4)));
struct H2 { _Float16 x, y; };   // (hi, lo)

__device__ __forceinline__ float2 cmulf(float2 a, float2 b) {
    return make_float2(a.x * b.x - a.y * b.y, a.x * b.y + a.y * b.x);
}

__device__ __forceinline__ float2 unitize(float2 v) {
    float m2 = v.x * v.x + v.y * v.y;
    if (m2 > 0.f) {
        float inv = 1.0f / sqrtf(m2);
        return make_float2(v.x * inv, v.y * inv);
    }
    return make_float2(1.f, 0.f);
}

__device__ __forceinline__ H2 split_h2(float v) {
    _Float16 h = (_Float16)v;
    float lo = v - (float)h;
    H2 r; r.x = h; r.y = (_Float16)lo; return r;
}

// o[k] = sum_n in[n] * (-i)^(n*k)
__device__ __forceinline__ void dft4(float2 a, float2 b, float2 c, float2 d,
                                     float2& o0, float2& o1, float2& o2, float2& o3) {
    float2 apc = make_float2(a.x + c.x, a.y + c.y);
    float2 amc = make_float2(a.x - c.x, a.y - c.y);
    float2 bpd = make_float2(b.x + d.x, b.y + d.y);
    float2 bmd = make_float2(b.x - d.x, b.y - d.y);
    o0 = make_float2(apc.x + bpd.x, apc.y + bpd.y);
    o1 = make_float2(amc.x + bmd.y, amc.y - bmd.x);   // amc - i*bmd
    o2 = make_float2(apc.x - bpd.x, apc.y - bpd.y);
    o3 = make_float2(amc.x - bmd.y, amc.y + bmd.x);   // amc + i*bmd
}

// ---------------------------------------------------------------------------
// Kernel 1: twiddle table W[k] = exp(-2*pi*i*k/4096), fp64-computed
// ---------------------------------------------------------------------------
__global__ void twiddle_init(float2* __restrict__ W) {
    int k = blockIdx.x * 256 + threadIdx.x;
    double ang = -2.0 * 3.14159265358979323846 * (double)k / 4096.0;
    W[k] = make_float2((float)cos(ang), (float)sin(ang));
}

// ---------------------------------------------------------------------------
// Kernel 2: transpose (b, s, f) -> (b, f, s) fp32
// ---------------------------------------------------------------------------
__global__ __launch_bounds__(256) void transpose_kernel(
        const float* __restrict__ q, float* __restrict__ qt) {
    __shared__ float tile[32][33];
    int b = blockIdx.z;
    int s0 = blockIdx.x * 32;
    int f0 = blockIdx.y * 32;
    int tx = threadIdx.x;
    int ty = threadIdx.y;
    const float* qb = q + (size_t)b * NS * NF;
    float* qtb = qt + (size_t)b * NF * NS;
#pragma unroll
    for (int i = 0; i < 4; ++i) {
        int s = s0 + ty + i * 8;
        tile[ty + i * 8][tx] = qb[(size_t)s * NF + f0 + tx];
    }
    __syncthreads();
#pragma unroll
    for (int i = 0; i < 4; ++i) {
        int f = f0 + ty + i * 8;
        qtb[(size_t)f * NS + s0 + tx] = tile[tx][ty + i * 8];
    }
}

// ---------------------------------------------------------------------------
// Radix-16 Stockham 4096-pt FFT: 3 stages (s = 1, 16, 256), 256 threads.
// A->B, B->A, A->B: result in B.
// ---------------------------------------------------------------------------
__device__ __forceinline__ void fft4096_r16(float2* A, float2* B,
                                            const float2* __restrict__ W, int t) {
    const float C1 = 0.92387953251128674f;   // cos(pi/8)
    const float S1 = 0.38268343236508978f;   // sin(pi/8)
    const float R2 = 0.70710678118654752f;
    const float2 w1 = make_float2(C1, -S1);
    const float2 w2 = make_float2(R2, -R2);
    const float2 w3 = make_float2(S1, -C1);
    const float2 w4 = make_float2(0.f, -1.f);
    const float2 w6 = make_float2(-R2, -R2);
    const float2 w9 = make_float2(-C1, S1);
#pragma unroll
    for (int st = 0; st < 3; ++st) {
        float2* src = (st == 1) ? B : A;
        float2* dst = (st == 1) ? A : B;
        const int s = (st == 0) ? 1 : (st == 1) ? 16 : 256;
        __syncthreads();
        float2 x[16];
#pragma unroll
        for (int j = 0; j < 16; ++j) x[j] = src[SWZF(t + j * 256)];
        float2 y[4][4];   // y[n0][k0]
#pragma unroll
        for (int n0 = 0; n0 < 4; ++n0)
            dft4(x[n0], x[4 + n0], x[8 + n0], x[12 + n0],
                 y[n0][0], y[n0][1], y[n0][2], y[n0][3]);
        y[1][1] = cmulf(w1, y[1][1]);
        y[1][2] = cmulf(w2, y[1][2]);
        y[1][3] = cmulf(w3, y[1][3]);
        y[2][1] = cmulf(w2, y[2][1]);
        y[2][2] = cmulf(w4, y[2][2]);
        y[2][3] = cmulf(w6, y[2][3]);
        y[3][1] = cmulf(w3, y[3][1]);
        y[3][2] = cmulf(w6, y[3][2]);
        y[3][3] = cmulf(w9, y[3][3]);
        float2 z[16];
#pragma unroll
        for (int k0 = 0; k0 < 4; ++k0)
            dft4(y[0][k0], y[1][k0], y[2][k0], y[3][k0],
                 z[k0], z[4 + k0], z[8 + k0], z[12 + k0]);
        const int q = t & (s - 1);
        const int pw = t - q;
        const int dbase = 16 * t - 15 * q;
        dst[SWZF(dbase)] = z[0];
        if (st == 2) {
#pragma unroll
            for (int j = 1; j < 16; ++j)
                dst[SWZF(dbase + j * s)] = z[j];
        } else {
#pragma unroll
            for (int j = 1; j < 16; ++j)
                dst[SWZF(dbase + j * s)] = cmulf(W[(j * pw) & 4095], z[j]);
        }
    }
}

// ---------------------------------------------------------------------------
// Kernel 3: two rows per block (two-for-one real FFT both directions);
// epilogue emits scaled fp16 (hi,lo) splits into U2 [b*512+f][s].
// ---------------------------------------------------------------------------
__global__ __launch_bounds__(256) void fft_phase_kernel(
        const float* __restrict__ qt, H2* __restrict__ u2,
        const float2* __restrict__ W) {
    __shared__ float2 bufA[4096];
    __shared__ float2 bufB[4096];
    const int t = threadIdx.x;
    const float* x0 = qt + (size_t)(2 * blockIdx.x) * NS;
    const float* x1 = x0 + NS;

    const float4* a4 = (const float4*)x0;
    const float4* b4 = (const float4*)x1;
#pragma unroll
    for (int i = 0; i < 4; ++i) {
        int idx = t + i * 256;
        float4 va = a4[idx];
        float4 vb = b4[idx];
        bufA[SWZF(idx * 4 + 0)] = make_float2(va.x, vb.x);
        bufA[SWZF(idx * 4 + 1)] = make_float2(va.y, vb.y);
        bufA[SWZF(idx * 4 + 2)] = make_float2(va.z, vb.z);
        bufA[SWZF(idx * 4 + 3)] = make_float2(va.w, vb.w);
    }

    fft4096_r16(bufA, bufB, W, t);      // Z = FFT(x0 + i*x1) in bufB
    __syncthreads();

    // Unpack X0, X1; normalize; repack V = U0 + i*U1 (both Hermitian).
#pragma unroll
    for (int j = 0; j < 8; ++j) {
        int k = t + j * 256;            // 0..2047
        if (k == 0) {
            float2 z0 = bufB[SWZF(0)];
            float2 zh = bufB[SWZF(2048)];
            float2 u00 = unitize(make_float2(z0.x, 0.f));
            float2 u10 = unitize(make_float2(z0.y, 0.f));
            bufB[SWZF(0)] = make_float2(u00.x, u10.x);
            float2 u0h = unitize(make_float2(zh.x, 0.f));
            float2 u1h = unitize(make_float2(zh.y, 0.f));
            bufB[SWZF(2048)] = make_float2(u0h.x, u1h.x);
        } else {
            float2 zk = bufB[SWZF(k)];
            float2 zm = bufB[SWZF(4096 - k)];
            float2 a = make_float2(0.5f * (zk.x + zm.x), 0.5f * (zk.y - zm.y));
            float2 bq = make_float2(0.5f * (zk.x - zm.x), 0.5f * (zk.y + zm.y));
            float2 x1k = make_float2(bq.y, -bq.x);
            float2 u0 = unitize(a);
            float2 u1 = unitize(x1k);
            bufB[SWZF(k)] = make_float2(u0.x - u1.y, u0.y + u1.x);
            bufB[SWZF(4096 - k)] = make_float2(u0.x + u1.y, u1.x - u0.y);
        }
    }

    fft4096_r16(bufB, bufA, W, t);      // F = FFT(V) in bufA
    __syncthreads();

    H2* o0 = u2 + (size_t)(2 * blockIdx.x) * NS;
    H2* o1 = o0 + NS;
    const float c = 0.25f;              // (1/4096) * 1024
#pragma unroll
    for (int i = 0; i < 4; ++i) {
        int idx = t + i * 256;
        H2 t0[4], t1[4];
#pragma unroll
        for (int k = 0; k < 4; ++k) {
            float2 e = bufA[SWZF(idx * 4 + k)];
            t0[k] = split_h2(e.x * c);
            t1[k] = split_h2(e.y * c);
        }
        *(float4*)&o0[idx * 4] = *(float4*)t0;
        *(float4*)&o1[idx * 4] = *(float4*)t1;
    }
}

// ---------------------------------------------------------------------------
// Kernel 4: A3-builder: U2 [f][s] (H2) -> fragment-major A3.
// Thread (s, qd) handles 16 f-halves for one row -> two 1KB-row slots.
// ---------------------------------------------------------------------------
__global__ __launch_bounds__(256) void abuild_kernel(
        const H2* __restrict__ u2, _Float16* __restrict__ a3) {
    __shared__ H2 tile[64][65];
    const int b = blockIdx.z;
    const int f0 = blockIdx.y * 64;
    const int s0 = blockIdx.x * 64;
    const int t = threadIdx.x;
    const int fr = t >> 6;        // 0..3
    const int sc = t & 63;
#pragma unroll
    for (int i = 0; i < 16; ++i) {
        int f = fr + i * 4;
        tile[f][sc] = u2[(size_t)(b * NF + f0 + f) * NS + s0 + sc];
    }
    __syncthreads();
    const int s = t >> 2;         // 0..63
    const int qd = t & 3;         // f block of 16
    _Float16 xs[16], ys[16];
#pragma unroll
    for (int j = 0; j < 16; ++j) {
        H2 v = tile[qd * 16 + j][s];
        xs[j] = v.x;
        ys[j] = v.y;
    }
    const int f = f0 + qd * 16;           // 16-aligned
    const int s_g = b * NS + s0 + s;
    const int rb = s_g >> 4;
    const int sl = s_g & 15;
    const int kc = f >> 5;
    const int g0 = (f >> 3) & 3;          // in {0, 2}
    size_t base = ((size_t)rb * 32 + kc) * 512;
    *(float4*)(a3 + base + (g0 * 16 + sl) * 8) = ((float4*)xs)[0];
    *(float4*)(a3 + base + ((g0 + 1) * 16 + sl) * 8) = ((float4*)xs)[1];
    base += 16 * 512;                     // lo -> kc + 16
    *(float4*)(a3 + base + (g0 * 16 + sl) * 8) = ((float4*)ys)[0];
    *(float4*)(a3 + base + ((g0 + 1) * 16 + sl) * 8) = ((float4*)ys)[1];
}

// ---------------------------------------------------------------------------
// Kernel 5: B3-builder: items [n][f] f32 -> fragment-major B3.
// ---------------------------------------------------------------------------
__global__ __launch_bounds__(256) void bbuild_kernel(
        const float* __restrict__ items, _Float16* __restrict__ b3) {
    int id = blockIdx.x * 256 + threadIdx.x;   // 1024*128
    int n = id >> 7, fq = id & 127;
    int f = fq * 4;
    float4 v = *(const float4*)&items[(size_t)n * NF + f];
    H2 h0 = split_h2(v.x * 1024.f);
    H2 h1 = split_h2(v.y * 1024.f);
    H2 h2v = split_h2(v.z * 1024.f);
    H2 h3 = split_h2(v.w * 1024.f);
    _Float16 hs[4] = {h0.x, h1.x, h2v.x, h3.x};
    _Float16 ls[4] = {h0.y, h1.y, h2v.y, h3.y};
    const int rb = n >> 4, nl = n & 15;
    const int kc = f >> 5, g = (f >> 3) & 3, off = f & 7;   // off in {0,4}
    size_t base = ((size_t)rb * 32 + kc) * 512 + (g * 16 + nl) * 8 + off;
    *(float2*)(b3 + base) = *(float2*)hs;
    *(float2*)(b3 + base + 16 * 512) = *(float2*)ls;
}

// ---------------------------------------------------------------------------
// Kernel 6: MFMA score GEMM + fused per-(row, n-chunk) argmax. NO LDS staging,
// NO main-loop barriers: fragment-major operands, coalesced 1KB frag loads,
// software-pipelined one chunk ahead in registers.
// Block 128 rows x 128 n, 4 waves (2x2), per-wave 64x64 = 4x4 MFMA frags.
// Per 32-half chunk: 16 frag loads (A/B, hi+lo) + 48 MFMAs
// (Ahi*Bhi + Alo*Bhi + Ahi*Blo).
// ---------------------------------------------------------------------------
__global__ __launch_bounds__(256, 2) void gemm_mfma_argmax(
        const _Float16* __restrict__ a3, const _Float16* __restrict__ b3,
        float* __restrict__ pbest, int* __restrict__ pidx) {
    __shared__ float smemf[256];
    __shared__ int smemi[256];
    const int sb = blockIdx.x;      // 0..255
    const int kb = blockIdx.y;      // 0..7
    const int row0 = sb * 128;
    const int n0 = kb * 128;
    const int t = threadIdx.x;
    const int wid = t >> 6, l = t & 63, g = l >> 4, c = l & 15;
    const int wr = wid >> 1, wc = wid & 1;

    floatx4 acc[4][4];
#pragma unroll
    for (int m = 0; m < 4; ++m)
#pragma unroll
        for (int n = 0; n < 4; ++n) acc[m][n] = (floatx4)0.f;

    // frag (m, kc) at pa + m*16384 + kc*512 (halves); hi kc=ch, lo kc=16+ch
    const _Float16* pa = a3 + ((size_t)(sb * 8 + wr * 4) * 32) * 512 + l * 8;
    const _Float16* pb = b3 + ((size_t)(kb * 8 + wc * 4) * 32) * 512 + l * 8;

    half8 cah[4], cal[4], cbh[4], cbl[4];
    half8 nah[4], nal[4], nbh[4], nbl[4];

#define LOADF(ah, al, bh, bl, ch)                                           \
    {                                                                       \
        _Pragma("unroll") for (int m = 0; m < 4; ++m) {                     \
            ah[m] = *(const half8*)(pa + m * 16384 + (ch) * 512);           \
            al[m] = *(const half8*)(pa + m * 16384 + (16 + (ch)) * 512);    \
        }                                                                   \
        _Pragma("unroll") for (int n = 0; n < 4; ++n) {                     \
            bh[n] = *(const half8*)(pb + n * 16384 + (ch) * 512);           \
            bl[n] = *(const half8*)(pb + n * 16384 + (16 + (ch)) * 512);    \
        }                                                                   \
    }

#define MFMAS(ah, al, bh, bl)                                               \
    {                                                                       \
        _Pragma("unroll") for (int m = 0; m < 4; ++m)                       \
        _Pragma("unroll") for (int n = 0; n < 4; ++n) {                     \
            acc[m][n] = __builtin_amdgcn_mfma_f32_16x16x32_f16(             \
                ah[m], bh[n], acc[m][n], 0, 0, 0);                          \
            acc[m][n] = __builtin_amdgcn_mfma_f32_16x16x32_f16(             \
                al[m], bh[n], acc[m][n], 0, 0, 0);                          \
            acc[m][n] = __builtin_amdgcn_mfma_f32_16x16x32_f16(             \
                ah[m], bl[n], acc[m][n], 0, 0, 0);                          \
        }                                                                   \
    }

    LOADF(cah, cal, cbh, cbl, 0);
    for (int c0 = 0; c0 < 16; c0 += 2) {
        if (c0 + 1 < 16) LOADF(nah, nal, nbh, nbl, c0 + 1);
        MFMAS(cah, cal, cbh, cbl);
        if (c0 + 2 < 16) LOADF(cah, cal, cbh, cbl, c0 + 2);
        MFMAS(nah, nal, nbh, nbl);
    }
#undef LOADF
#undef MFMAS

    // argmax: per-thread over 4 n-frags, then across 16-lane row group,
    // then across the 2 wc wave columns via LDS.
#pragma unroll
    for (int m = 0; m < 4; ++m) {
#pragma unroll
        for (int rr = 0; rr < 4; ++rr) {
            float best = acc[m][0][rr];
            int bi = c;                    // n-frag 0, col c
#pragma unroll
            for (int n = 1; n < 4; ++n) {
                float v = acc[m][n][rr];
                int ig = n * 16 + c;
                if (v > best) { best = v; bi = ig; }
            }
#pragma unroll
            for (int off = 1; off < 16; off <<= 1) {
                float ov = __shfl_xor(best, off);
                int oi = __shfl_xor(bi, off);
                if (ov > best || (ov == best && oi < bi)) { best = ov; bi = oi; }
            }
            if (c == 0) {
                int s_local = wr * 64 + m * 16 + 4 * g + rr;
                smemf[wc * 128 + s_local] = best;
                smemi[wc * 128 + s_local] = bi;   // 0..63 within wave n-slice
            }
        }
    }
    __syncthreads();
    if (t < 128) {
        float b0v = smemf[t];
        int b0i = smemi[t];
        float b1v = smemf[128 + t];
        int b1i = smemi[128 + t] + 64;
        float best = b0v; int bi = b0i;
        if (b1v > b0v) { best = b1v; bi = b1i; }   // tie keeps lower (wc=0)
        int row = row0 + t;
        pbest[(size_t)row * NKB + kb] = best;
        pidx[(size_t)row * NKB + kb] = n0 + bi;
    }
}

// ---------------------------------------------------------------------------
// Kernel 7: combine partials (ascending n-chunk, strict >) + SSE vs queries
// ---------------------------------------------------------------------------
__global__ __launch_bounds__(256) void combine_loss_kernel(
        const float* __restrict__ q, const float* __restrict__ items,
        const float* __restrict__ pbest, const int* __restrict__ pidx,
        float* __restrict__ out) {
    const int wid = threadIdx.x >> 6;
    const int lane = threadIdx.x & 63;
    const int row = blockIdx.x * 4 + wid;

    float best = pbest[(size_t)row * NKB];
    int bidx = pidx[(size_t)row * NKB];
#pragma unroll
    for (int g = 1; g < NKB; ++g) {
        float v = pbest[(size_t)row * NKB + g];
        if (v > best) { best = v; bidx = pidx[(size_t)row * NKB + g]; }
    }

    const float4* qr = (const float4*)(q + (size_t)row * NF);
    const float4* mr = (const float4*)(items + (size_t)bidx * NF);
    float sum = 0.f;
#pragma unroll
    for (int i = 0; i < 2; ++i) {
        float4 a = qr[lane + i * 64];
        float4 m = mr[lane + i * 64];
        float dx = a.x - m.x, dy = a.y - m.y, dz = a.z - m.z, dw = a.w - m.w;
        sum += dx * dx + dy * dy + dz * dz + dw * dw;
    }
#pragma unroll
    for (int off = 32; off; off >>= 1) sum += __shfl_down(sum, off, 64);
    if (lane == 0) out[row] = sum;
}

// ---------------------------------------------------------------------------
extern "C" void kernel_launch(void* const* d_in, const int* in_sizes, int n_in,
                              void* d_out, int out_size, void* d_ws, size_t ws_size,
                              hipStream_t stream) {
    const float* q = (const float*)d_in[0];
    const float* items = (const float*)d_in[1];
    float* out = (float*)d_out;

    char* ws = (char*)d_ws;
    // Layout (132.1 MB total):
    //   [0]        W       32 KB
    //   [32K]      qt/A3   64 MB   (fp32 qt for FFT, then overwritten by A3)
    //   [32K+64M]  U2      64 MB   (H2 [4096][4096])
    //   [+64M]     B3       2 MB
    //   [+2M]      pbest    1 MB
    //   [+1M]      pidx     1 MB
    float2* W = (float2*)ws;
    float* qt = (float*)(ws + 32768);
    _Float16* a3 = (_Float16*)(ws + 32768);
    H2* u2 = (H2*)(ws + 32768 + (size_t)67108864);
    _Float16* b3 = (_Float16*)(ws + 32768 + (size_t)67108864 * 2);
    float* pbest = (float*)(ws + 32768 + (size_t)67108864 * 2 + 2097152);
    int* pidx = (int*)(ws + 32768 + (size_t)67108864 * 2 + 2097152 + 1048576);

    hipLaunchKernelGGL(twiddle_init, dim3(16), dim3(256), 0, stream, W);
    hipLaunchKernelGGL(transpose_kernel, dim3(128, 16, 8), dim3(32, 8, 1), 0,
                       stream, q, qt);
    hipLaunchKernelGGL(fft_phase_kernel, dim3(2048), dim3(256), 0, stream,
                       qt, u2, W);
    hipLaunchKernelGGL(abuild_kernel, dim3(64, 8, 8), dim3(256), 0, stream,
                       u2, a3);
    hipLaunchKernelGGL(bbuild_kernel, dim3(512), dim3(256), 0, stream,
                       items, b3);
    hipLaunchKernelGGL(gemm_mfma_argmax, dim3(256, 8), dim3(256), 0, stream,
                       a3, b3, pbest, pidx);
    hipLaunchKernelGGL(combine_loss_kernel, dim3(NROWS / 4), dim3(256), 0,
                       stream, q, items, pbest, pidx, out);
}